// Round 1
// baseline (1379.904 us; speedup 1.0000x reference)
//
#include <hip/hip_runtime.h>
#include <hip/hip_bf16.h>
#include <math.h>

#define N_NODES 100000
#define N_EDGES 1600000
#define N_USER  90000
#define NB1     352   // ceil(N_USER/256)

// ---------------- hp + attention logits (one layer) ----------------
// hp[n*128 + h*64 + o] = sum_f h[n,f] * w[h,f,o]   (nhf layout for edge gathers)
// attn_src[n*2+h] = dot(hp[n,h,:], a_src[h,:]); same for attn_trg
__global__ __launch_bounds__(256) void hp_attn_kernel(
    const float* __restrict__ h, const float* __restrict__ w,
    const float* __restrict__ a_src, const float* __restrict__ a_trg,
    float* __restrict__ hp, float* __restrict__ attn_src, float* __restrict__ attn_trg)
{
  __shared__ float Ws[64 * 128];   // Ws[f*128 + h*64 + o]
  for (int i = threadIdx.x; i < 64 * 128; i += 256) {
    int f = i >> 7, c = i & 127;
    Ws[i] = w[(c >> 6) * 4096 + f * 64 + (c & 63)];
  }
  __syncthreads();
  const int lane = threadIdx.x & 63;
  const int wave = threadIdx.x >> 6;
  const float as0 = a_src[lane], as1 = a_src[64 + lane];
  const float at0 = a_trg[lane], at1 = a_trg[64 + lane];
  const int nwaves = gridDim.x * 4;
  for (int p = blockIdx.x * 4 + wave; p * 2 < N_NODES; p += nwaves) {
    int n0 = 2 * p, n1 = 2 * p + 1;
    float hv0 = h[n0 * 64 + lane];
    float hv1 = h[n1 * 64 + lane];
    float a00 = 0.f, a01 = 0.f, a10 = 0.f, a11 = 0.f;  // a<node><head>
    #pragma unroll
    for (int f = 0; f < 64; ++f) {
      float wsa = Ws[f * 128 + lane];
      float wsb = Ws[f * 128 + 64 + lane];
      float h0 = __shfl(hv0, f, 64);
      float h1 = __shfl(hv1, f, 64);
      a00 += h0 * wsa; a01 += h0 * wsb;
      a10 += h1 * wsa; a11 += h1 * wsb;
    }
    hp[n0 * 128 + lane] = a00; hp[n0 * 128 + 64 + lane] = a01;
    hp[n1 * 128 + lane] = a10; hp[n1 * 128 + 64 + lane] = a11;
    float r0 = a00 * as0, r1 = a01 * as1, r2 = a00 * at0, r3 = a01 * at1;
    float r4 = a10 * as0, r5 = a11 * as1, r6 = a10 * at0, r7 = a11 * at1;
    #pragma unroll
    for (int off = 32; off; off >>= 1) {
      r0 += __shfl_down(r0, off, 64); r1 += __shfl_down(r1, off, 64);
      r2 += __shfl_down(r2, off, 64); r3 += __shfl_down(r3, off, 64);
      r4 += __shfl_down(r4, off, 64); r5 += __shfl_down(r5, off, 64);
      r6 += __shfl_down(r6, off, 64); r7 += __shfl_down(r7, off, 64);
    }
    if (lane == 0) {
      attn_src[n0 * 2] = r0; attn_src[n0 * 2 + 1] = r1;
      attn_trg[n0 * 2] = r2; attn_trg[n0 * 2 + 1] = r3;
      attn_src[n1 * 2] = r4; attn_src[n1 * 2 + 1] = r5;
      attn_trg[n1 * 2] = r6; attn_trg[n1 * 2 + 1] = r7;
    }
  }
}

// ---------------- CSR build ----------------
__global__ __launch_bounds__(256) void hist_kernel(const int* __restrict__ trg, int* __restrict__ count)
{
  int e = blockIdx.x * 256 + threadIdx.x;
  if (e < N_EDGES) {
    int t = trg[e];
    if (t < N_USER) atomicAdd(&count[t], 1);
  }
}

__global__ __launch_bounds__(256) void scan1_kernel(const int* __restrict__ count,
                                                    int* __restrict__ offs, int* __restrict__ aux)
{
  __shared__ int s[256];
  int i = blockIdx.x * 256 + threadIdx.x;
  int v = (i < N_USER) ? count[i] : 0;
  s[threadIdx.x] = v;
  __syncthreads();
  for (int d = 1; d < 256; d <<= 1) {
    int t = (threadIdx.x >= d) ? s[threadIdx.x - d] : 0;
    __syncthreads();
    s[threadIdx.x] += t;
    __syncthreads();
  }
  if (i < N_USER) offs[i] = s[threadIdx.x] - v;   // exclusive within block
  if (threadIdx.x == 255) aux[blockIdx.x] = s[255];
}

__global__ __launch_bounds__(512) void scan2_kernel(const int* __restrict__ aux, int* __restrict__ auxex)
{
  __shared__ int s[512];
  int v = (threadIdx.x < NB1) ? aux[threadIdx.x] : 0;
  s[threadIdx.x] = v;
  __syncthreads();
  for (int d = 1; d < 512; d <<= 1) {
    int t = (threadIdx.x >= d) ? s[threadIdx.x - d] : 0;
    __syncthreads();
    s[threadIdx.x] += t;
    __syncthreads();
  }
  if (threadIdx.x < NB1) auxex[threadIdx.x] = s[threadIdx.x] - v;
  if (threadIdx.x == 511) auxex[NB1] = s[511];
}

__global__ __launch_bounds__(256) void scan3_kernel(int* __restrict__ offs, int* __restrict__ cursor,
                                                    const int* __restrict__ auxex)
{
  int i = blockIdx.x * 256 + threadIdx.x;
  if (i < N_USER) {
    int o = offs[i] + auxex[blockIdx.x];
    offs[i] = o;
    cursor[i] = o;
  }
  if (i == 0) offs[N_USER] = auxex[NB1];
}

__global__ __launch_bounds__(256) void scatter_kernel(const int* __restrict__ src, const int* __restrict__ trg,
                                                      int* __restrict__ cursor, int* __restrict__ csr_src)
{
  int e = blockIdx.x * 256 + threadIdx.x;
  if (e < N_EDGES) {
    int t = trg[e];
    if (t < N_USER) {
      int p = atomicAdd(&cursor[t], 1);
      csr_src[p] = src[e];
    }
  }
}

// ---------------- per-target accumulation (softmax folded in) ----------------
// Global max subtraction in the reference cancels in exp/denom; skipped (no overflow: |e| <~ 12).
__global__ __launch_bounds__(256) void accum_kernel(const int* __restrict__ offs, const int* __restrict__ csr_src,
                                                    const float* __restrict__ attn_src, const float* __restrict__ attn_trg,
                                                    const float* __restrict__ hp, float* __restrict__ x)
{
  const int lane = threadIdx.x & 63;
  const int wave = threadIdx.x >> 6;
  int n = blockIdx.x * 4 + wave;
  if (n >= N_USER) return;
  int beg = offs[n], end = offs[n + 1];
  float at0 = attn_trg[n * 2], at1 = attn_trg[n * 2 + 1];
  float acc0 = 0.f, acc1 = 0.f, den0 = 0.f, den1 = 0.f;
  for (int i = beg; i < end; ++i) {
    int s = csr_src[i];
    float as0 = attn_src[s * 2], as1 = attn_src[s * 2 + 1];
    float e0 = as0 + at0; e0 = (e0 > 0.f) ? e0 : 0.2f * e0;
    float e1 = as1 + at1; e1 = (e1 > 0.f) ? e1 : 0.2f * e1;
    float w0 = __expf(e0), w1 = __expf(e1);
    den0 += w0; den1 += w1;
    acc0 += w0 * hp[s * 128 + lane];
    acc1 += w1 * hp[s * 128 + 64 + lane];
  }
  // mean over H=2 heads
  x[n * 64 + lane] = 0.5f * (acc0 / (den0 + 1e-16f) + acc1 / (den1 + 1e-16f));
}

// ---------------- fusion head + fc + log_softmax ----------------
__global__ __launch_bounds__(1024) void final_kernel(
    const float* __restrict__ h, const float* __restrict__ x0, const float* __restrict__ x1,
    const float* __restrict__ aa_w1, const float* __restrict__ aa_w2,
    const float* __restrict__ aa_m, const float* __restrict__ fc_w, const float* __restrict__ fc_b,
    float* __restrict__ out)
{
  __shared__ float w1t[64 * 64];   // transposed: w1t[f*64+d] = aa_w1[d,f]
  __shared__ float w2t[64 * 64];
  __shared__ float aam[64];
  __shared__ float fcw[2 * 192];
  __shared__ float fcb[2];
  for (int i = threadIdx.x; i < 4096; i += 1024) {
    int f = i >> 6, d = i & 63;
    w1t[i] = aa_w1[d * 64 + f];
    w2t[i] = aa_w2[d * 64 + f];
  }
  if (threadIdx.x < 64)  aam[threadIdx.x] = aa_m[threadIdx.x];
  if (threadIdx.x < 384) fcw[threadIdx.x] = fc_w[threadIdx.x];
  if (threadIdx.x < 2)   fcb[threadIdx.x] = fc_b[threadIdx.x];
  __syncthreads();
  const int lane = threadIdx.x & 63;
  const int wave = threadIdx.x >> 6;
  int n = blockIdx.x * 16 + wave;
  if (n >= N_USER) return;
  float hr  = h[n * 64 + lane];
  float xr0 = x0[n * 64 + lane];
  float xr1 = x1[n * 64 + lane];
  float t1 = 0.f, t20 = 0.f, t21 = 0.f;     // lane = d
  #pragma unroll
  for (int f = 0; f < 64; ++f) {
    float hf  = __shfl(hr,  f, 64);
    float x0f = __shfl(xr0, f, 64);
    float x1f = __shfl(xr1, f, 64);
    float w1v = w1t[f * 64 + lane];
    float w2v = w2t[f * 64 + lane];
    t1  += w1v * hf;
    t20 += w2v * x0f;
    t21 += w2v * x1f;
  }
  float q0 = tanhf(t1 + t20);
  float q1 = tanhf(t1 + t21);
  float am = aam[lane];
  float s0 = q0 * am, s1 = q1 * am;
  #pragma unroll
  for (int m = 32; m; m >>= 1) { s0 += __shfl_xor(s0, m, 64); s1 += __shfl_xor(s1, m, 64); }
  float mx = fmaxf(s0, s1);
  float e0 = __expf(s0 - mx), e1 = __expf(s1 - mx);
  float inv = 1.f / (e0 + e1);
  float b0 = e0 * inv, b1 = e1 * inv;
  float fus = b0 * xr0 + b1 * xr1;          // lane = o
  float p0 = fcw[lane] * xr0 + fcw[64 + lane] * xr1 + fcw[128 + lane] * fus;
  float p1 = fcw[192 + lane] * xr0 + fcw[256 + lane] * xr1 + fcw[320 + lane] * fus;
  #pragma unroll
  for (int m = 32; m; m >>= 1) { p0 += __shfl_xor(p0, m, 64); p1 += __shfl_xor(p1, m, 64); }
  float l0 = p0 + fcb[0], l1 = p1 + fcb[1];
  float lm = fmaxf(l0, l1);
  float lse = lm + logf(__expf(l0 - lm) + __expf(l1 - lm));
  if (lane == 0) { out[n * 2] = l0 - lse; out[n * 2 + 1] = l1 - lse; }
}

extern "C" void kernel_launch(void* const* d_in, const int* in_sizes, int n_in,
                              void* d_out, int out_size, void* d_ws, size_t ws_size,
                              hipStream_t stream)
{
  const float* h     = (const float*)d_in[0];
  const int*   src0  = (const int*)d_in[1];
  const int*   trg0  = (const int*)d_in[2];
  const int*   src1  = (const int*)d_in[3];
  const int*   trg1  = (const int*)d_in[4];
  const float* w0    = (const float*)d_in[5];
  const float* asrc0 = (const float*)d_in[6];
  const float* atrg0 = (const float*)d_in[7];
  const float* w1    = (const float*)d_in[8];
  const float* asrc1 = (const float*)d_in[9];
  const float* atrg1 = (const float*)d_in[10];
  const float* aa_w1 = (const float*)d_in[11];
  const float* aa_w2 = (const float*)d_in[12];
  const float* aa_m  = (const float*)d_in[13];
  const float* fc_w  = (const float*)d_in[14];
  const float* fc_b  = (const float*)d_in[15];
  float* out = (float*)d_out;

  char* ws = (char*)d_ws;
  size_t off = 0;
  auto alloc = [&](size_t bytes) -> void* {
    void* p = ws + off;
    off = (off + bytes + 255) & ~(size_t)255;
    return p;
  };
  float* hp       = (float*)alloc((size_t)N_NODES * 128 * 4);   // 51.2 MB (reused per layer)
  float* attn_src = (float*)alloc((size_t)N_NODES * 2 * 4);
  float* attn_trg = (float*)alloc((size_t)N_NODES * 2 * 4);
  float* x0       = (float*)alloc((size_t)N_USER * 64 * 4);     // 23 MB
  float* x1       = (float*)alloc((size_t)N_USER * 64 * 4);
  int*   count    = (int*)alloc((size_t)N_USER * 4);
  int*   offs     = (int*)alloc((size_t)(N_USER + 1) * 4);
  int*   cursor   = (int*)alloc((size_t)N_USER * 4);
  int*   aux      = (int*)alloc((size_t)NB1 * 4);
  int*   auxex    = (int*)alloc((size_t)(NB1 + 1) * 4);
  int*   csr      = (int*)alloc((size_t)N_EDGES * 4);           // 6.4 MB

  const int EB = (N_EDGES + 255) / 256;   // 6250
  for (int layer = 0; layer < 2; ++layer) {
    const float* w    = layer ? w1 : w0;
    const float* asrc = layer ? asrc1 : asrc0;
    const float* atrg = layer ? atrg1 : atrg0;
    const int*   src  = layer ? src1 : src0;
    const int*   trg  = layer ? trg1 : trg0;
    float*       x    = layer ? x1 : x0;
    hipLaunchKernelGGL(hp_attn_kernel, dim3(1024), dim3(256), 0, stream,
                       h, w, asrc, atrg, hp, attn_src, attn_trg);
    hipMemsetAsync(count, 0, (size_t)N_USER * 4, stream);
    hipLaunchKernelGGL(hist_kernel, dim3(EB), dim3(256), 0, stream, trg, count);
    hipLaunchKernelGGL(scan1_kernel, dim3(NB1), dim3(256), 0, stream, count, offs, aux);
    hipLaunchKernelGGL(scan2_kernel, dim3(1), dim3(512), 0, stream, aux, auxex);
    hipLaunchKernelGGL(scan3_kernel, dim3(NB1), dim3(256), 0, stream, offs, cursor, auxex);
    hipLaunchKernelGGL(scatter_kernel, dim3(EB), dim3(256), 0, stream, src, trg, cursor, csr);
    hipLaunchKernelGGL(accum_kernel, dim3(N_USER / 4), dim3(256), 0, stream,
                       offs, csr, attn_src, attn_trg, hp, x);
  }
  hipLaunchKernelGGL(final_kernel, dim3(N_USER / 16), dim3(1024), 0, stream,
                     h, x0, x1, aa_w1, aa_w2, aa_m, fc_w, fc_b, out);
}

// Round 2
// 1119.320 us; speedup vs baseline: 1.2328x; 1.2328x over previous
//
#include <hip/hip_runtime.h>
#include <hip/hip_bf16.h>
#include <math.h>

#define N_NODES 100000
#define N_EDGES 1600000
#define N_USER  90000
#define NB1     352   // ceil(N_USER/256)

// broadcast lane f's value to all lanes via v_readlane (VALU/SGPR path, NOT the LDS pipe)
__device__ __forceinline__ float rl(float v, int l) {
  return __int_as_float(__builtin_amdgcn_readlane(__float_as_int(v), l));
}
__device__ __forceinline__ float fast_tanh(float x) {
  float t = __expf(2.f * x);           // inf for large x -> returns 1; 0 for very negative -> -1
  return 1.f - 2.f / (t + 1.f);
}

// ---------------- hp + attention logits (one layer) ----------------
// hp[n*128 + h*64 + o] = sum_f h[n,f] * w[h,f,o]   (nhf layout for edge gathers)
// 512 threads = 8 waves, 4 nodes per wave; weights from LDS (2 reads/f amortized
// over 4 nodes), h broadcast via readlane (VALU) instead of shfl (LDS pipe).
__global__ __launch_bounds__(512) void hp_attn_kernel(
    const float* __restrict__ h, const float* __restrict__ w,
    const float* __restrict__ a_src, const float* __restrict__ a_trg,
    float* __restrict__ hp, float* __restrict__ attn_src, float* __restrict__ attn_trg)
{
  __shared__ float Ws[64 * 128];   // Ws[f*128 + hd*64 + o]
  for (int i = threadIdx.x; i < 8192; i += 512) {
    int hd = i >> 12, r = i & 4095, f = r >> 6, o = r & 63;
    Ws[f * 128 + hd * 64 + o] = w[i];
  }
  __syncthreads();
  const int lane = threadIdx.x & 63;
  const int wv = threadIdx.x >> 6;
  const float as0 = a_src[lane], as1 = a_src[64 + lane];
  const float at0 = a_trg[lane], at1 = a_trg[64 + lane];
  const int n0 = blockIdx.x * 32 + wv * 4;       // 3125 blocks * 32 = 100000 exactly
  float h0 = h[(n0 + 0) * 64 + lane];
  float h1 = h[(n0 + 1) * 64 + lane];
  float h2 = h[(n0 + 2) * 64 + lane];
  float h3 = h[(n0 + 3) * 64 + lane];
  float a00 = 0.f, a01 = 0.f, a10 = 0.f, a11 = 0.f;
  float a20 = 0.f, a21 = 0.f, a30 = 0.f, a31 = 0.f;
  #pragma unroll
  for (int f = 0; f < 64; ++f) {
    float wsa = Ws[f * 128 + lane];
    float wsb = Ws[f * 128 + 64 + lane];
    float f0 = rl(h0, f), f1 = rl(h1, f), f2 = rl(h2, f), f3 = rl(h3, f);
    a00 += f0 * wsa; a01 += f0 * wsb;
    a10 += f1 * wsa; a11 += f1 * wsb;
    a20 += f2 * wsa; a21 += f2 * wsb;
    a30 += f3 * wsa; a31 += f3 * wsb;
  }
  float A0[4] = {a00, a10, a20, a30};
  float A1[4] = {a01, a11, a21, a31};
  #pragma unroll
  for (int j = 0; j < 4; ++j) {
    int n = n0 + j;
    hp[n * 128 + lane]      = A0[j];
    hp[n * 128 + 64 + lane] = A1[j];
    float r0 = A0[j] * as0, r1 = A1[j] * as1, r2 = A0[j] * at0, r3 = A1[j] * at1;
    #pragma unroll
    for (int m = 32; m; m >>= 1) {
      r0 += __shfl_xor(r0, m, 64); r1 += __shfl_xor(r1, m, 64);
      r2 += __shfl_xor(r2, m, 64); r3 += __shfl_xor(r3, m, 64);
    }
    if (lane == 0) {
      attn_src[n * 2] = r0; attn_src[n * 2 + 1] = r1;
      attn_trg[n * 2] = r2; attn_trg[n * 2 + 1] = r3;
    }
  }
}

// ---------------- CSR build ----------------
__global__ __launch_bounds__(256) void hist_kernel(const int* __restrict__ trg, int* __restrict__ count)
{
  int e = blockIdx.x * 256 + threadIdx.x;
  if (e < N_EDGES) {
    int t = trg[e];
    if (t < N_USER) atomicAdd(&count[t], 1);
  }
}

__global__ __launch_bounds__(256) void scan1_kernel(const int* __restrict__ count,
                                                    int* __restrict__ offs, int* __restrict__ aux)
{
  __shared__ int s[256];
  int i = blockIdx.x * 256 + threadIdx.x;
  int v = (i < N_USER) ? count[i] : 0;
  s[threadIdx.x] = v;
  __syncthreads();
  for (int d = 1; d < 256; d <<= 1) {
    int t = (threadIdx.x >= d) ? s[threadIdx.x - d] : 0;
    __syncthreads();
    s[threadIdx.x] += t;
    __syncthreads();
  }
  if (i < N_USER) offs[i] = s[threadIdx.x] - v;   // exclusive within block
  if (threadIdx.x == 255) aux[blockIdx.x] = s[255];
}

__global__ __launch_bounds__(512) void scan2_kernel(const int* __restrict__ aux, int* __restrict__ auxex)
{
  __shared__ int s[512];
  int v = (threadIdx.x < NB1) ? aux[threadIdx.x] : 0;
  s[threadIdx.x] = v;
  __syncthreads();
  for (int d = 1; d < 512; d <<= 1) {
    int t = (threadIdx.x >= d) ? s[threadIdx.x - d] : 0;
    __syncthreads();
    s[threadIdx.x] += t;
    __syncthreads();
  }
  if (threadIdx.x < NB1) auxex[threadIdx.x] = s[threadIdx.x] - v;
  if (threadIdx.x == 511) auxex[NB1] = s[511];
}

__global__ __launch_bounds__(256) void scan3_kernel(int* __restrict__ offs, int* __restrict__ cursor,
                                                    const int* __restrict__ auxex)
{
  int i = blockIdx.x * 256 + threadIdx.x;
  if (i < N_USER) {
    int o = offs[i] + auxex[blockIdx.x];
    offs[i] = o;
    cursor[i] = o;
  }
  if (i == 0) offs[N_USER] = auxex[NB1];
}

__global__ __launch_bounds__(256) void scatter_kernel(const int* __restrict__ src, const int* __restrict__ trg,
                                                      int* __restrict__ cursor, int* __restrict__ csr_src)
{
  int e = blockIdx.x * 256 + threadIdx.x;
  if (e < N_EDGES) {
    int t = trg[e];
    if (t < N_USER) {
      int p = atomicAdd(&cursor[t], 1);
      csr_src[p] = src[e];
    }
  }
}

// ---------------- per-target accumulation (softmax folded in) ----------------
// Global max subtraction in the reference cancels in exp/denom; skipped (no overflow: |e| <~ 12).
__global__ __launch_bounds__(256) void accum_kernel(const int* __restrict__ offs, const int* __restrict__ csr_src,
                                                    const float* __restrict__ attn_src, const float* __restrict__ attn_trg,
                                                    const float* __restrict__ hp, float* __restrict__ x)
{
  const int lane = threadIdx.x & 63;
  const int wave = threadIdx.x >> 6;
  int n = blockIdx.x * 4 + wave;
  if (n >= N_USER) return;
  int beg = offs[n], end = offs[n + 1];
  float at0 = attn_trg[n * 2], at1 = attn_trg[n * 2 + 1];
  float acc0 = 0.f, acc1 = 0.f, den0 = 0.f, den1 = 0.f;
  for (int i = beg; i < end; ++i) {
    int s = csr_src[i];
    float as0 = attn_src[s * 2], as1 = attn_src[s * 2 + 1];
    float e0 = as0 + at0; e0 = (e0 > 0.f) ? e0 : 0.2f * e0;
    float e1 = as1 + at1; e1 = (e1 > 0.f) ? e1 : 0.2f * e1;
    float w0 = __expf(e0), w1 = __expf(e1);
    den0 += w0; den1 += w1;
    acc0 += w0 * hp[s * 128 + lane];
    acc1 += w1 * hp[s * 128 + 64 + lane];
  }
  // mean over H=2 heads
  x[n * 64 + lane] = 0.5f * (acc0 / (den0 + 1e-16f) + acc1 / (den1 + 1e-16f));
}

// ---------------- fusion head + fc + log_softmax ----------------
// 512 threads = 8 waves, 4 nodes/wave. Weights (transposed, pitch 65) in LDS;
// per-node vector broadcasts via readlane.
__global__ __launch_bounds__(512) void final_kernel(
    const float* __restrict__ h, const float* __restrict__ x0, const float* __restrict__ x1,
    const float* __restrict__ aa_w1, const float* __restrict__ aa_w2,
    const float* __restrict__ aa_m, const float* __restrict__ fc_w, const float* __restrict__ fc_b,
    float* __restrict__ out)
{
  __shared__ float w1s[64 * 65];   // w1s[f*65+d] = aa_w1[d,f] (pitch 65: conflict-free both ways)
  __shared__ float w2s[64 * 65];
  __shared__ float aam[64];
  __shared__ float fcw[384];
  __shared__ float fcb[2];
  for (int i = threadIdx.x; i < 4096; i += 512) {
    int d = i >> 6, f = i & 63;
    w1s[f * 65 + d] = aa_w1[i];
    w2s[f * 65 + d] = aa_w2[i];
  }
  if (threadIdx.x < 64)  aam[threadIdx.x] = aa_m[threadIdx.x];
  if (threadIdx.x < 384) fcw[threadIdx.x] = fc_w[threadIdx.x];
  if (threadIdx.x < 2)   fcb[threadIdx.x] = fc_b[threadIdx.x];
  __syncthreads();
  const int lane = threadIdx.x & 63;
  const int wv = threadIdx.x >> 6;
  const int n0 = blockIdx.x * 32 + wv * 4;
  int nc[4];
  float hr[4], x0r[4], x1r[4];
  float t1[4] = {0.f, 0.f, 0.f, 0.f};
  float t20[4] = {0.f, 0.f, 0.f, 0.f};
  float t21[4] = {0.f, 0.f, 0.f, 0.f};
  #pragma unroll
  for (int j = 0; j < 4; ++j) {
    nc[j] = (n0 + j < N_USER) ? (n0 + j) : (N_USER - 1);
    hr[j]  = h[nc[j] * 64 + lane];
    x0r[j] = x0[nc[j] * 64 + lane];
    x1r[j] = x1[nc[j] * 64 + lane];
  }
  #pragma unroll
  for (int f = 0; f < 64; ++f) {
    float w1v = w1s[f * 65 + lane];
    float w2v = w2s[f * 65 + lane];
    #pragma unroll
    for (int j = 0; j < 4; ++j) {
      t1[j]  += rl(hr[j], f)  * w1v;
      t20[j] += rl(x0r[j], f) * w2v;
      t21[j] += rl(x1r[j], f) * w2v;
    }
  }
  float am = aam[lane];
  #pragma unroll
  for (int j = 0; j < 4; ++j) {
    float q0 = fast_tanh(t1[j] + t20[j]);
    float q1 = fast_tanh(t1[j] + t21[j]);
    float s0 = q0 * am, s1 = q1 * am;
    #pragma unroll
    for (int m = 32; m; m >>= 1) { s0 += __shfl_xor(s0, m, 64); s1 += __shfl_xor(s1, m, 64); }
    float mx = fmaxf(s0, s1);
    float e0 = __expf(s0 - mx), e1 = __expf(s1 - mx);
    float inv = 1.f / (e0 + e1);
    float b0 = e0 * inv, b1 = e1 * inv;
    float fus = b0 * x0r[j] + b1 * x1r[j];          // lane = output dim o
    float p0 = fcw[lane] * x0r[j] + fcw[64 + lane] * x1r[j] + fcw[128 + lane] * fus;
    float p1 = fcw[192 + lane] * x0r[j] + fcw[256 + lane] * x1r[j] + fcw[320 + lane] * fus;
    #pragma unroll
    for (int m = 32; m; m >>= 1) { p0 += __shfl_xor(p0, m, 64); p1 += __shfl_xor(p1, m, 64); }
    if (lane == 0 && n0 + j < N_USER) {
      float l0 = p0 + fcb[0], l1 = p1 + fcb[1];
      float lm = fmaxf(l0, l1);
      float lse = lm + logf(__expf(l0 - lm) + __expf(l1 - lm));
      out[(n0 + j) * 2] = l0 - lse;
      out[(n0 + j) * 2 + 1] = l1 - lse;
    }
  }
}

extern "C" void kernel_launch(void* const* d_in, const int* in_sizes, int n_in,
                              void* d_out, int out_size, void* d_ws, size_t ws_size,
                              hipStream_t stream)
{
  const float* h     = (const float*)d_in[0];
  const int*   src0  = (const int*)d_in[1];
  const int*   trg0  = (const int*)d_in[2];
  const int*   src1  = (const int*)d_in[3];
  const int*   trg1  = (const int*)d_in[4];
  const float* w0    = (const float*)d_in[5];
  const float* asrc0 = (const float*)d_in[6];
  const float* atrg0 = (const float*)d_in[7];
  const float* w1    = (const float*)d_in[8];
  const float* asrc1 = (const float*)d_in[9];
  const float* atrg1 = (const float*)d_in[10];
  const float* aa_w1 = (const float*)d_in[11];
  const float* aa_w2 = (const float*)d_in[12];
  const float* aa_m  = (const float*)d_in[13];
  const float* fc_w  = (const float*)d_in[14];
  const float* fc_b  = (const float*)d_in[15];
  float* out = (float*)d_out;

  char* ws = (char*)d_ws;
  size_t off = 0;
  auto alloc = [&](size_t bytes) -> void* {
    void* p = ws + off;
    off = (off + bytes + 255) & ~(size_t)255;
    return p;
  };
  float* hp       = (float*)alloc((size_t)N_NODES * 128 * 4);   // 51.2 MB (reused per layer)
  float* attn_src = (float*)alloc((size_t)N_NODES * 2 * 4);
  float* attn_trg = (float*)alloc((size_t)N_NODES * 2 * 4);
  float* x0       = (float*)alloc((size_t)N_USER * 64 * 4);     // 23 MB
  float* x1       = (float*)alloc((size_t)N_USER * 64 * 4);
  int*   count    = (int*)alloc((size_t)N_USER * 4);
  int*   offs     = (int*)alloc((size_t)(N_USER + 1) * 4);
  int*   cursor   = (int*)alloc((size_t)N_USER * 4);
  int*   aux      = (int*)alloc((size_t)NB1 * 4);
  int*   auxex    = (int*)alloc((size_t)(NB1 + 1) * 4);
  int*   csr      = (int*)alloc((size_t)N_EDGES * 4);           // 6.4 MB

  const int EB = (N_EDGES + 255) / 256;   // 6250
  for (int layer = 0; layer < 2; ++layer) {
    const float* w    = layer ? w1 : w0;
    const float* asrc = layer ? asrc1 : asrc0;
    const float* atrg = layer ? atrg1 : atrg0;
    const int*   src  = layer ? src1 : src0;
    const int*   trg  = layer ? trg1 : trg0;
    float*       x    = layer ? x1 : x0;
    hipLaunchKernelGGL(hp_attn_kernel, dim3(N_NODES / 32), dim3(512), 0, stream,
                       h, w, asrc, atrg, hp, attn_src, attn_trg);
    hipMemsetAsync(count, 0, (size_t)N_USER * 4, stream);
    hipLaunchKernelGGL(hist_kernel, dim3(EB), dim3(256), 0, stream, trg, count);
    hipLaunchKernelGGL(scan1_kernel, dim3(NB1), dim3(256), 0, stream, count, offs, aux);
    hipLaunchKernelGGL(scan2_kernel, dim3(1), dim3(512), 0, stream, aux, auxex);
    hipLaunchKernelGGL(scan3_kernel, dim3(NB1), dim3(256), 0, stream, offs, cursor, auxex);
    hipLaunchKernelGGL(scatter_kernel, dim3(EB), dim3(256), 0, stream, src, trg, cursor, csr);
    hipLaunchKernelGGL(accum_kernel, dim3(N_USER / 4), dim3(256), 0, stream,
                       offs, csr, attn_src, attn_trg, hp, x);
  }
  hipLaunchKernelGGL(final_kernel, dim3((N_USER + 31) / 32), dim3(512), 0, stream,
                     h, x0, x1, aa_w1, aa_w2, aa_m, fc_w, fc_b, out);
}

// Round 7
// 1000.980 us; speedup vs baseline: 1.3786x; 1.1182x over previous
//
#include <hip/hip_runtime.h>
#include <hip/hip_bf16.h>
#include <math.h>

#define N_NODES 100000
#define N_EDGES 1600000
#define N_USER  90000
#define NB1     352   // ceil(N_USER/256)

typedef __attribute__((ext_vector_type(8))) short  short8;   // 8 bf16 (4 VGPRs) MFMA A/B frag
typedef __attribute__((ext_vector_type(4))) float  floatx4;  // MFMA C/D frag
typedef unsigned int  uint;
typedef unsigned short ushort;

__device__ __forceinline__ ushort f2bf(float x) {            // RNE fp32 -> bf16
  uint u = __float_as_uint(x);
  u += 0x7fffu + ((u >> 16) & 1u);
  return (ushort)(u >> 16);
}
__device__ __forceinline__ float bf2f(ushort v) { return __uint_as_float(((uint)v) << 16); }

__device__ __forceinline__ void split8(const float v[8], short8& hi, short8& lo) {
  #pragma unroll
  for (int j = 0; j < 8; ++j) {
    ushort h = f2bf(v[j]);
    hi[j] = (short)h;
    lo[j] = (short)f2bf(v[j] - bf2f(h));
  }
}
__device__ __forceinline__ void load_split8(const float* p, short8& hi, short8& lo) {
  const float4* q = (const float4*)p;
  float4 a = q[0], b = q[1];
  float v[8] = {a.x, a.y, a.z, a.w, b.x, b.y, b.z, b.w};
  split8(v, hi, lo);
}
__device__ __forceinline__ float rl(float v, int l) {
  return __int_as_float(__builtin_amdgcn_readlane(__float_as_int(v), l));
}
__device__ __forceinline__ float fast_tanh(float x) {
  float t = __expf(2.f * x);
  return 1.f - 2.f / (t + 1.f);
}

// ---------------- hp via MFMA, fp32 output in R2's layout (one layer) ----------------
// hp[n*128 + head*64 + o], attn_src[n*2+head], attn_trg[n*2+head] — all fp32,
// identical buffers/contents to R2's hp_attn_kernel (which passed). ONLY the
// producer differs (MFMA instead of readlane-FMA). Single-variable experiment.
__global__ __launch_bounds__(256) void hp_mfma(
    const float* __restrict__ h, const float* __restrict__ w,
    const float* __restrict__ a_src, const float* __restrict__ a_trg,
    float* __restrict__ hp, float* __restrict__ attn_src, float* __restrict__ attn_trg)
{
  __shared__ float part[4][16][4];          // [wave][row][as0,as1,at0,at1]
  const int tid = threadIdx.x, lane = tid & 63, wv = tid >> 6;
  const int quad = lane >> 4, l15 = lane & 15;
  const int o = wv * 16 + l15;              // wave's 16-col slice of the 64 outputs
  const float vas0 = a_src[o], vas1 = a_src[64 + o];
  const float vat0 = a_trg[o], vat1 = a_trg[64 + o];
  short8 b0h[2], b0l[2], b1h[2], b1l[2];    // B frags: head0/head1 x ksteps
  #pragma unroll
  for (int ks = 0; ks < 2; ++ks) {
    float v0[8], v1[8];
    #pragma unroll
    for (int j = 0; j < 8; ++j) {
      int k = quad * 8 + j + ks * 32;       // f index
      v0[j] = w[k * 64 + o];                // w[0][f][o]
      v1[j] = w[4096 + k * 64 + o];         // w[1][f][o]
    }
    split8(v0, b0h[ks], b0l[ks]);
    split8(v1, b1h[ks], b1l[ks]);
  }
  for (int t = blockIdx.x; t < N_NODES / 16; t += gridDim.x) {
    int m0 = t * 16, arow = m0 + l15;
    short8 ah[2], al[2];
    #pragma unroll
    for (int ks = 0; ks < 2; ++ks)
      load_split8(h + arow * 64 + quad * 8 + ks * 32, ah[ks], al[ks]);
    floatx4 c0 = {0.f, 0.f, 0.f, 0.f}, c1 = {0.f, 0.f, 0.f, 0.f};
    #pragma unroll
    for (int ks = 0; ks < 2; ++ks) {
      c0 = __builtin_amdgcn_mfma_f32_16x16x32_bf16(ah[ks], b0h[ks], c0, 0, 0, 0);
      c0 = __builtin_amdgcn_mfma_f32_16x16x32_bf16(ah[ks], b0l[ks], c0, 0, 0, 0);
      c0 = __builtin_amdgcn_mfma_f32_16x16x32_bf16(al[ks], b0h[ks], c0, 0, 0, 0);
      c1 = __builtin_amdgcn_mfma_f32_16x16x32_bf16(ah[ks], b1h[ks], c1, 0, 0, 0);
      c1 = __builtin_amdgcn_mfma_f32_16x16x32_bf16(ah[ks], b1l[ks], c1, 0, 0, 0);
      c1 = __builtin_amdgcn_mfma_f32_16x16x32_bf16(al[ks], b1h[ks], c1, 0, 0, 0);
    }
    // fp32 hp store in R2 layout; C/D map: col=l15 (o), row=quad*4+r
    #pragma unroll
    for (int r = 0; r < 4; ++r) {
      int n = m0 + quad * 4 + r;
      hp[n * 128 + o]      = c0[r];
      hp[n * 128 + 64 + o] = c1[r];
    }
    // exact fp32 attention logits from C regs: butterfly over l15, then waves via LDS
    #pragma unroll
    for (int r = 0; r < 4; ++r) {
      float pas0 = c0[r] * vas0, pas1 = c1[r] * vas1;
      float pat0 = c0[r] * vat0, pat1 = c1[r] * vat1;
      #pragma unroll
      for (int m = 1; m < 16; m <<= 1) {
        pas0 += __shfl_xor(pas0, m, 64); pas1 += __shfl_xor(pas1, m, 64);
        pat0 += __shfl_xor(pat0, m, 64); pat1 += __shfl_xor(pat1, m, 64);
      }
      if (l15 == 0) {
        part[wv][quad * 4 + r][0] = pas0; part[wv][quad * 4 + r][1] = pas1;
        part[wv][quad * 4 + r][2] = pat0; part[wv][quad * 4 + r][3] = pat1;
      }
    }
    __syncthreads();
    if (tid < 64) {
      int row = tid & 15, which = tid >> 4;
      float v = part[0][row][which] + part[1][row][which]
              + part[2][row][which] + part[3][row][which];
      int n = m0 + row;
      if (which == 0)      attn_src[n * 2]     = v;
      else if (which == 1) attn_src[n * 2 + 1] = v;
      else if (which == 2) attn_trg[n * 2]     = v;
      else                 attn_trg[n * 2 + 1] = v;
    }
    __syncthreads();                        // part[] reuse next tile
  }
}

// ---------------- CSR build (verbatim from passing R2) ----------------
__global__ __launch_bounds__(256) void hist_kernel(const int* __restrict__ trg, int* __restrict__ count)
{
  int e = blockIdx.x * 256 + threadIdx.x;
  if (e < N_EDGES) {
    int t = trg[e];
    if (t < N_USER) atomicAdd(&count[t], 1);
  }
}

__global__ __launch_bounds__(256) void scan1_kernel(const int* __restrict__ count,
                                                    int* __restrict__ offs, int* __restrict__ aux)
{
  __shared__ int s[256];
  int i = blockIdx.x * 256 + threadIdx.x;
  int v = (i < N_USER) ? count[i] : 0;
  s[threadIdx.x] = v;
  __syncthreads();
  for (int d = 1; d < 256; d <<= 1) {
    int t = (threadIdx.x >= d) ? s[threadIdx.x - d] : 0;
    __syncthreads();
    s[threadIdx.x] += t;
    __syncthreads();
  }
  if (i < N_USER) offs[i] = s[threadIdx.x] - v;
  if (threadIdx.x == 255) aux[blockIdx.x] = s[255];
}

__global__ __launch_bounds__(512) void scan2_kernel(const int* __restrict__ aux, int* __restrict__ auxex)
{
  __shared__ int s[512];
  int v = (threadIdx.x < NB1) ? aux[threadIdx.x] : 0;
  s[threadIdx.x] = v;
  __syncthreads();
  for (int d = 1; d < 512; d <<= 1) {
    int t = (threadIdx.x >= d) ? s[threadIdx.x - d] : 0;
    __syncthreads();
    s[threadIdx.x] += t;
    __syncthreads();
  }
  if (threadIdx.x < NB1) auxex[threadIdx.x] = s[threadIdx.x] - v;
  if (threadIdx.x == 511) auxex[NB1] = s[511];
}

__global__ __launch_bounds__(256) void scan3_kernel(int* __restrict__ offs, int* __restrict__ cursor,
                                                    const int* __restrict__ auxex)
{
  int i = blockIdx.x * 256 + threadIdx.x;
  if (i < N_USER) {
    int o = offs[i] + auxex[blockIdx.x];
    offs[i] = o;
    cursor[i] = o;
  }
  if (i == 0) offs[N_USER] = auxex[NB1];
}

__global__ __launch_bounds__(256) void scatter_kernel(const int* __restrict__ src, const int* __restrict__ trg,
                                                      int* __restrict__ cursor, int* __restrict__ csr_src)
{
  int e = blockIdx.x * 256 + threadIdx.x;
  if (e < N_EDGES) {
    int t = trg[e];
    if (t < N_USER) {
      int p = atomicAdd(&cursor[t], 1);
      csr_src[p] = src[e];
    }
  }
}

// ---------------- per-target accumulation (R2-verbatim fp32 + bounds clamps) ----------------
__global__ __launch_bounds__(256) void accum_kernel(const int* __restrict__ offs, const int* __restrict__ csr_src,
                                                    const float* __restrict__ attn_src, const float* __restrict__ attn_trg,
                                                    const float* __restrict__ hp, float* __restrict__ x)
{
  const int lane = threadIdx.x & 63;
  const int wave = threadIdx.x >> 6;
  int n = blockIdx.x * 4 + wave;
  if (n >= N_USER) return;
  int beg = offs[n], end = offs[n + 1];
  beg = max(0, beg);
  end = min(end, N_EDGES);
  float at0 = attn_trg[n * 2], at1 = attn_trg[n * 2 + 1];
  float acc0 = 0.f, acc1 = 0.f, den0 = 0.f, den1 = 0.f;
  for (int i = beg; i < end; ++i) {
    int s = csr_src[i];
    s = min(max(s, 0), N_NODES - 1);
    float as0 = attn_src[s * 2], as1 = attn_src[s * 2 + 1];
    float e0 = as0 + at0; e0 = (e0 > 0.f) ? e0 : 0.2f * e0;
    float e1 = as1 + at1; e1 = (e1 > 0.f) ? e1 : 0.2f * e1;
    float w0 = __expf(e0), w1 = __expf(e1);
    den0 += w0; den1 += w1;
    acc0 += w0 * hp[s * 128 + lane];
    acc1 += w1 * hp[s * 128 + 64 + lane];
  }
  x[n * 64 + lane] = 0.5f * (acc0 / (den0 + 1e-16f) + acc1 / (den1 + 1e-16f));
}

// ---------------- fusion head + fc + log_softmax (R2-verbatim, passed) ----------------
__global__ __launch_bounds__(512) void final_kernel(
    const float* __restrict__ h, const float* __restrict__ x0, const float* __restrict__ x1,
    const float* __restrict__ aa_w1, const float* __restrict__ aa_w2,
    const float* __restrict__ aa_m, const float* __restrict__ fc_w, const float* __restrict__ fc_b,
    float* __restrict__ out)
{
  __shared__ float w1s[64 * 65];   // w1s[f*65+d] = aa_w1[d,f]
  __shared__ float w2s[64 * 65];
  __shared__ float aam[64];
  __shared__ float fcw[384];
  __shared__ float fcb[2];
  for (int i = threadIdx.x; i < 4096; i += 512) {
    int d = i >> 6, f = i & 63;
    w1s[f * 65 + d] = aa_w1[i];
    w2s[f * 65 + d] = aa_w2[i];
  }
  if (threadIdx.x < 64)  aam[threadIdx.x] = aa_m[threadIdx.x];
  if (threadIdx.x < 384) fcw[threadIdx.x] = fc_w[threadIdx.x];
  if (threadIdx.x < 2)   fcb[threadIdx.x] = fc_b[threadIdx.x];
  __syncthreads();
  const int lane = threadIdx.x & 63;
  const int wv = threadIdx.x >> 6;
  const int n0 = blockIdx.x * 32 + wv * 4;
  int nc[4];
  float hr[4], x0r[4], x1r[4];
  float t1[4] = {0.f, 0.f, 0.f, 0.f};
  float t20[4] = {0.f, 0.f, 0.f, 0.f};
  float t21[4] = {0.f, 0.f, 0.f, 0.f};
  #pragma unroll
  for (int j = 0; j < 4; ++j) {
    nc[j] = (n0 + j < N_USER) ? (n0 + j) : (N_USER - 1);
    hr[j]  = h[nc[j] * 64 + lane];
    x0r[j] = x0[nc[j] * 64 + lane];
    x1r[j] = x1[nc[j] * 64 + lane];
  }
  #pragma unroll
  for (int f = 0; f < 64; ++f) {
    float w1v = w1s[f * 65 + lane];
    float w2v = w2s[f * 65 + lane];
    #pragma unroll
    for (int j = 0; j < 4; ++j) {
      t1[j]  += rl(hr[j], f)  * w1v;
      t20[j] += rl(x0r[j], f) * w2v;
      t21[j] += rl(x1r[j], f) * w2v;
    }
  }
  float am = aam[lane];
  #pragma unroll
  for (int j = 0; j < 4; ++j) {
    float q0 = fast_tanh(t1[j] + t20[j]);
    float q1 = fast_tanh(t1[j] + t21[j]);
    float s0 = q0 * am, s1 = q1 * am;
    #pragma unroll
    for (int m = 32; m; m >>= 1) { s0 += __shfl_xor(s0, m, 64); s1 += __shfl_xor(s1, m, 64); }
    float mx = fmaxf(s0, s1);
    float e0 = __expf(s0 - mx), e1 = __expf(s1 - mx);
    float inv = 1.f / (e0 + e1);
    float b0 = e0 * inv, b1 = e1 * inv;
    float fus = b0 * x0r[j] + b1 * x1r[j];
    float p0 = fcw[lane] * x0r[j] + fcw[64 + lane] * x1r[j] + fcw[128 + lane] * fus;
    float p1 = fcw[192 + lane] * x0r[j] + fcw[256 + lane] * x1r[j] + fcw[320 + lane] * fus;
    #pragma unroll
    for (int m = 32; m; m >>= 1) { p0 += __shfl_xor(p0, m, 64); p1 += __shfl_xor(p1, m, 64); }
    if (lane == 0 && n0 + j < N_USER) {
      float l0 = p0 + fcb[0], l1 = p1 + fcb[1];
      float lm = fmaxf(l0, l1);
      float lse = lm + logf(__expf(l0 - lm) + __expf(l1 - lm));
      out[(n0 + j) * 2] = l0 - lse;
      out[(n0 + j) * 2 + 1] = l1 - lse;
    }
  }
}

extern "C" void kernel_launch(void* const* d_in, const int* in_sizes, int n_in,
                              void* d_out, int out_size, void* d_ws, size_t ws_size,
                              hipStream_t stream)
{
  const float* h     = (const float*)d_in[0];
  const int*   src0  = (const int*)d_in[1];
  const int*   trg0  = (const int*)d_in[2];
  const int*   src1  = (const int*)d_in[3];
  const int*   trg1  = (const int*)d_in[4];
  const float* w0    = (const float*)d_in[5];
  const float* asrc0 = (const float*)d_in[6];
  const float* atrg0 = (const float*)d_in[7];
  const float* w1    = (const float*)d_in[8];
  const float* asrc1 = (const float*)d_in[9];
  const float* atrg1 = (const float*)d_in[10];
  const float* aa_w1 = (const float*)d_in[11];
  const float* aa_w2 = (const float*)d_in[12];
  const float* aa_m  = (const float*)d_in[13];
  const float* fc_w  = (const float*)d_in[14];
  const float* fc_b  = (const float*)d_in[15];
  float* out = (float*)d_out;

  char* ws = (char*)d_ws;
  size_t off = 0;
  auto alloc = [&](size_t bytes) -> void* {
    void* p = ws + off;
    off = (off + bytes + 255) & ~(size_t)255;
    return p;
  };
  // total ~106 MB == R2's proven-pass footprint (identical layout)
  float* hp       = (float*)alloc((size_t)N_NODES * 128 * 4);   // 51.2 MB, reused per layer
  float* attn_src = (float*)alloc((size_t)N_NODES * 2 * 4);
  float* attn_trg = (float*)alloc((size_t)N_NODES * 2 * 4);
  float* x0       = (float*)alloc((size_t)N_USER * 64 * 4);     // 23 MB
  float* x1       = (float*)alloc((size_t)N_USER * 64 * 4);
  int*   count    = (int*)alloc((size_t)N_USER * 4);
  int*   offs     = (int*)alloc((size_t)(N_USER + 1) * 4);
  int*   cursor   = (int*)alloc((size_t)N_USER * 4);
  int*   aux      = (int*)alloc((size_t)NB1 * 4);
  int*   auxex    = (int*)alloc((size_t)(NB1 + 1) * 4);
  int*   csr      = (int*)alloc((size_t)N_EDGES * 4);           // 6.4 MB, reused per layer

  const int EB = (N_EDGES + 255) / 256;   // 6250
  for (int layer = 0; layer < 2; ++layer) {
    const float* w    = layer ? w1 : w0;
    const float* asrc = layer ? asrc1 : asrc0;
    const float* atrg = layer ? atrg1 : atrg0;
    const int*   src  = layer ? src1 : src0;
    const int*   trg  = layer ? trg1 : trg0;
    float*       x    = layer ? x1 : x0;
    hipLaunchKernelGGL(hp_mfma, dim3(1024), dim3(256), 0, stream,
                       h, w, asrc, atrg, hp, attn_src, attn_trg);
    hipMemsetAsync(count, 0, (size_t)N_USER * 4, stream);
    hipLaunchKernelGGL(hist_kernel, dim3(EB), dim3(256), 0, stream, trg, count);
    hipLaunchKernelGGL(scan1_kernel, dim3(NB1), dim3(256), 0, stream, count, offs, aux);
    hipLaunchKernelGGL(scan2_kernel, dim3(1), dim3(512), 0, stream, aux, auxex);
    hipLaunchKernelGGL(scan3_kernel, dim3(NB1), dim3(256), 0, stream, offs, cursor, auxex);
    hipLaunchKernelGGL(scatter_kernel, dim3(EB), dim3(256), 0, stream, src, trg, cursor, csr);
    hipLaunchKernelGGL(accum_kernel, dim3(N_USER / 4), dim3(256), 0, stream,
                       offs, csr, attn_src, attn_trg, hp, x);
  }
  hipLaunchKernelGGL(final_kernel, dim3((N_USER + 31) / 32), dim3(512), 0, stream,
                     h, x0, x1, aa_w1, aa_w2, aa_m, fc_w, fc_b, out);
}

// Round 8
// 907.005 us; speedup vs baseline: 1.5214x; 1.1036x over previous
//
#include <hip/hip_runtime.h>
#include <hip/hip_bf16.h>
#include <math.h>

#define N_NODES 100000
#define N_EDGES 1600000
#define N_USER  90000
#define NB1     352   // ceil(N_USER/256)

typedef __attribute__((ext_vector_type(8))) short  short8;   // 8 bf16 (4 VGPRs) MFMA A/B frag
typedef __attribute__((ext_vector_type(4))) float  floatx4;  // MFMA C/D frag
typedef unsigned int  uint;
typedef unsigned short ushort;

__device__ __forceinline__ ushort f2bf(float x) {            // RNE fp32 -> bf16
  uint u = __float_as_uint(x);
  u += 0x7fffu + ((u >> 16) & 1u);
  return (ushort)(u >> 16);
}
__device__ __forceinline__ float bf2f(ushort v) { return __uint_as_float(((uint)v) << 16); }

__device__ __forceinline__ void split8(const float v[8], short8& hi, short8& lo) {
  #pragma unroll
  for (int j = 0; j < 8; ++j) {
    ushort h = f2bf(v[j]);
    hi[j] = (short)h;
    lo[j] = (short)f2bf(v[j] - bf2f(h));
  }
}
__device__ __forceinline__ void load_split8(const float* p, short8& hi, short8& lo) {
  const float4* q = (const float4*)p;
  float4 a = q[0], b = q[1];
  float v[8] = {a.x, a.y, a.z, a.w, b.x, b.y, b.z, b.w};
  split8(v, hi, lo);
}
__device__ __forceinline__ float fast_tanh(float x) {
  float t = __expf(2.f * x);
  return 1.f - 2.f / (t + 1.f);
}

// ---------------- hp via MFMA -> packed bf16, exact fp32 logits (one layer) ----------------
// hpi[n*64+o] = pack(bf16 head0, bf16 head1); logits from fp32 C regs (as in passing R7).
__global__ __launch_bounds__(256) void hp_mfma(
    const float* __restrict__ h, const float* __restrict__ w,
    const float* __restrict__ a_src, const float* __restrict__ a_trg,
    uint* __restrict__ hpi, float* __restrict__ attn_src, float* __restrict__ attn_trg)
{
  __shared__ float part[4][16][4];          // [wave][row][as0,as1,at0,at1]
  const int tid = threadIdx.x, lane = tid & 63, wv = tid >> 6;
  const int quad = lane >> 4, l15 = lane & 15;
  const int o = wv * 16 + l15;              // wave's 16-col slice of the 64 outputs
  const float vas0 = a_src[o], vas1 = a_src[64 + o];
  const float vat0 = a_trg[o], vat1 = a_trg[64 + o];
  short8 b0h[2], b0l[2], b1h[2], b1l[2];    // B frags: head0/head1 x ksteps
  #pragma unroll
  for (int ks = 0; ks < 2; ++ks) {
    float v0[8], v1[8];
    #pragma unroll
    for (int j = 0; j < 8; ++j) {
      int k = quad * 8 + j + ks * 32;       // f index
      v0[j] = w[k * 64 + o];                // w[0][f][o]
      v1[j] = w[4096 + k * 64 + o];         // w[1][f][o]
    }
    split8(v0, b0h[ks], b0l[ks]);
    split8(v1, b1h[ks], b1l[ks]);
  }
  for (int t = blockIdx.x; t < N_NODES / 16; t += gridDim.x) {
    int m0 = t * 16, arow = m0 + l15;
    short8 ah[2], al[2];
    #pragma unroll
    for (int ks = 0; ks < 2; ++ks)
      load_split8(h + arow * 64 + quad * 8 + ks * 32, ah[ks], al[ks]);
    floatx4 c0 = {0.f, 0.f, 0.f, 0.f}, c1 = {0.f, 0.f, 0.f, 0.f};
    #pragma unroll
    for (int ks = 0; ks < 2; ++ks) {
      c0 = __builtin_amdgcn_mfma_f32_16x16x32_bf16(ah[ks], b0h[ks], c0, 0, 0, 0);
      c0 = __builtin_amdgcn_mfma_f32_16x16x32_bf16(ah[ks], b0l[ks], c0, 0, 0, 0);
      c0 = __builtin_amdgcn_mfma_f32_16x16x32_bf16(al[ks], b0h[ks], c0, 0, 0, 0);
      c1 = __builtin_amdgcn_mfma_f32_16x16x32_bf16(ah[ks], b1h[ks], c1, 0, 0, 0);
      c1 = __builtin_amdgcn_mfma_f32_16x16x32_bf16(ah[ks], b1l[ks], c1, 0, 0, 0);
      c1 = __builtin_amdgcn_mfma_f32_16x16x32_bf16(al[ks], b1h[ks], c1, 0, 0, 0);
    }
    // packed bf16 hp store; C/D map: col=l15 (o), row=quad*4+r
    #pragma unroll
    for (int r = 0; r < 4; ++r) {
      int n = m0 + quad * 4 + r;
      hpi[n * 64 + o] = (uint)f2bf(c0[r]) | ((uint)f2bf(c1[r]) << 16);
    }
    // exact fp32 logits from C regs: butterfly over l15, then waves via LDS
    #pragma unroll
    for (int r = 0; r < 4; ++r) {
      float pas0 = c0[r] * vas0, pas1 = c1[r] * vas1;
      float pat0 = c0[r] * vat0, pat1 = c1[r] * vat1;
      #pragma unroll
      for (int m = 1; m < 16; m <<= 1) {
        pas0 += __shfl_xor(pas0, m, 64); pas1 += __shfl_xor(pas1, m, 64);
        pat0 += __shfl_xor(pat0, m, 64); pat1 += __shfl_xor(pat1, m, 64);
      }
      if (l15 == 0) {
        part[wv][quad * 4 + r][0] = pas0; part[wv][quad * 4 + r][1] = pas1;
        part[wv][quad * 4 + r][2] = pat0; part[wv][quad * 4 + r][3] = pat1;
      }
    }
    __syncthreads();
    if (tid < 64) {
      int row = tid & 15, which = tid >> 4;
      float v = part[0][row][which] + part[1][row][which]
              + part[2][row][which] + part[3][row][which];
      int n = m0 + row;
      if (which == 0)      attn_src[n * 2]     = v;
      else if (which == 1) attn_src[n * 2 + 1] = v;
      else if (which == 2) attn_trg[n * 2]     = v;
      else                 attn_trg[n * 2 + 1] = v;
    }
    __syncthreads();                        // part[] reuse next tile
  }
}

// ---------------- CSR build (verbatim from passing R2/R7) ----------------
__global__ __launch_bounds__(256) void hist_kernel(const int* __restrict__ trg, int* __restrict__ count)
{
  int e = blockIdx.x * 256 + threadIdx.x;
  if (e < N_EDGES) {
    int t = trg[e];
    if (t < N_USER) atomicAdd(&count[t], 1);
  }
}

__global__ __launch_bounds__(256) void scan1_kernel(const int* __restrict__ count,
                                                    int* __restrict__ offs, int* __restrict__ aux)
{
  __shared__ int s[256];
  int i = blockIdx.x * 256 + threadIdx.x;
  int v = (i < N_USER) ? count[i] : 0;
  s[threadIdx.x] = v;
  __syncthreads();
  for (int d = 1; d < 256; d <<= 1) {
    int t = (threadIdx.x >= d) ? s[threadIdx.x - d] : 0;
    __syncthreads();
    s[threadIdx.x] += t;
    __syncthreads();
  }
  if (i < N_USER) offs[i] = s[threadIdx.x] - v;
  if (threadIdx.x == 255) aux[blockIdx.x] = s[255];
}

__global__ __launch_bounds__(512) void scan2_kernel(const int* __restrict__ aux, int* __restrict__ auxex)
{
  __shared__ int s[512];
  int v = (threadIdx.x < NB1) ? aux[threadIdx.x] : 0;
  s[threadIdx.x] = v;
  __syncthreads();
  for (int d = 1; d < 512; d <<= 1) {
    int t = (threadIdx.x >= d) ? s[threadIdx.x - d] : 0;
    __syncthreads();
    s[threadIdx.x] += t;
    __syncthreads();
  }
  if (threadIdx.x < NB1) auxex[threadIdx.x] = s[threadIdx.x] - v;
  if (threadIdx.x == 511) auxex[NB1] = s[511];
}

__global__ __launch_bounds__(256) void scan3_kernel(int* __restrict__ offs, int* __restrict__ cursor,
                                                    const int* __restrict__ auxex)
{
  int i = blockIdx.x * 256 + threadIdx.x;
  if (i < N_USER) {
    int o = offs[i] + auxex[blockIdx.x];
    offs[i] = o;
    cursor[i] = o;
  }
  if (i == 0) offs[N_USER] = auxex[NB1];
}

__global__ __launch_bounds__(256) void scatter_kernel(const int* __restrict__ src, const int* __restrict__ trg,
                                                      int* __restrict__ cursor, int* __restrict__ csr_src)
{
  int e = blockIdx.x * 256 + threadIdx.x;
  if (e < N_EDGES) {
    int t = trg[e];
    if (t < N_USER) {
      int p = atomicAdd(&cursor[t], 1);
      csr_src[p] = src[e];
    }
  }
}

// ---------------- per-target accumulation (softmax folded; bf16 hp gather) ----------------
// Global max subtraction cancels in exp/denom; skipped. Clamps = OOB insurance (identity).
__global__ __launch_bounds__(256) void accum_kernel(
    const int* __restrict__ offs, const int* __restrict__ csr_src,
    const float* __restrict__ attn_src, const float* __restrict__ attn_trg,
    const uint* __restrict__ hpi, float* __restrict__ x)
{
  const int lane = threadIdx.x & 63, wv = threadIdx.x >> 6;
  int n = blockIdx.x * 4 + wv;
  if (n >= N_USER) return;
  int beg = offs[n], end = offs[n + 1];
  beg = max(0, beg);
  end = min(end, N_EDGES);
  float at0 = attn_trg[n * 2], at1 = attn_trg[n * 2 + 1];
  float acc0 = 0.f, acc1 = 0.f, den0 = 0.f, den1 = 0.f;
  for (int i = beg; i < end; ++i) {
    int s = csr_src[i];
    s = min(max(s, 0), N_NODES - 1);
    uint pv = hpi[s * 64 + lane];
    float as0 = attn_src[s * 2], as1 = attn_src[s * 2 + 1];
    float e0 = as0 + at0; e0 = (e0 > 0.f) ? e0 : 0.2f * e0;
    float e1 = as1 + at1; e1 = (e1 > 0.f) ? e1 : 0.2f * e1;
    float w0 = __expf(e0), w1 = __expf(e1);
    den0 += w0; den1 += w1;
    acc0 += w0 * bf2f((ushort)(pv & 0xffff));
    acc1 += w1 * bf2f((ushort)(pv >> 16));
  }
  x[n * 64 + lane] = 0.5f * (acc0 / (den0 + 1e-16f) + acc1 / (den1 + 1e-16f));
}

// ---------------- final: 3 MFMA GEMMs + fused epilogue ----------------
// BUG FIXED vs R3-R6: fcw_s has 384 elems but block is 256 threads; the old
// `if (tid<384)` left fcw_s[256..383] as uninitialized LDS garbage -> the
// O(1-10) random absmax failures. Now a grid-stride load covers all 384.
__global__ __launch_bounds__(256) void final_mfma(
    const float* __restrict__ h, const float* __restrict__ x0, const float* __restrict__ x1,
    const float* __restrict__ aa_w1, const float* __restrict__ aa_w2, const float* __restrict__ aa_m,
    const float* __restrict__ fc_w, const float* __restrict__ fc_b, float* __restrict__ out)
{
  __shared__ float aam_s[64], fcw_s[384], fcb_s[2];
  __shared__ float scw0[4][16], scw1[4][16];   // per-wave partial scores
  const int tid = threadIdx.x;
  if (tid < 64)  aam_s[tid] = aa_m[tid];
  for (int i = tid; i < 384; i += 256) fcw_s[i] = fc_w[i];   // FIX: full coverage
  if (tid < 2)   fcb_s[tid] = fc_b[tid];
  const int lane = tid & 63, wv = tid >> 6, quad = lane >> 4, l15 = lane & 15;
  const int d = wv * 16 + l15;              // global output dim for GEMMs
  short8 b1h[2], b1l[2], b2h[2], b2l[2];    // B[k=f][n=d] = aa_w*[d*64+f]
  #pragma unroll
  for (int ks = 0; ks < 2; ++ks) {
    load_split8(aa_w1 + d * 64 + quad * 8 + ks * 32, b1h[ks], b1l[ks]);
    load_split8(aa_w2 + d * 64 + quad * 8 + ks * 32, b2h[ks], b2l[ks]);
  }
  __syncthreads();
  for (int t = blockIdx.x; t < N_USER / 16; t += gridDim.x) {
    int m0 = t * 16, arow = m0 + l15;
    short8 ahh[2], ahl[2], a0h[2], a0l[2], a1h[2], a1l[2];
    #pragma unroll
    for (int ks = 0; ks < 2; ++ks) {
      load_split8(h  + arow * 64 + quad * 8 + ks * 32, ahh[ks], ahl[ks]);
      load_split8(x0 + arow * 64 + quad * 8 + ks * 32, a0h[ks], a0l[ks]);
      load_split8(x1 + arow * 64 + quad * 8 + ks * 32, a1h[ks], a1l[ks]);
    }
    floatx4 t1a = {0.f,0.f,0.f,0.f}, t20a = {0.f,0.f,0.f,0.f}, t21a = {0.f,0.f,0.f,0.f};
    #pragma unroll
    for (int ks = 0; ks < 2; ++ks) {
      t1a  = __builtin_amdgcn_mfma_f32_16x16x32_bf16(ahh[ks], b1h[ks], t1a, 0, 0, 0);
      t1a  = __builtin_amdgcn_mfma_f32_16x16x32_bf16(ahh[ks], b1l[ks], t1a, 0, 0, 0);
      t1a  = __builtin_amdgcn_mfma_f32_16x16x32_bf16(ahl[ks], b1h[ks], t1a, 0, 0, 0);
      t20a = __builtin_amdgcn_mfma_f32_16x16x32_bf16(a0h[ks], b2h[ks], t20a, 0, 0, 0);
      t20a = __builtin_amdgcn_mfma_f32_16x16x32_bf16(a0h[ks], b2l[ks], t20a, 0, 0, 0);
      t20a = __builtin_amdgcn_mfma_f32_16x16x32_bf16(a0l[ks], b2h[ks], t20a, 0, 0, 0);
      t21a = __builtin_amdgcn_mfma_f32_16x16x32_bf16(a1h[ks], b2h[ks], t21a, 0, 0, 0);
      t21a = __builtin_amdgcn_mfma_f32_16x16x32_bf16(a1h[ks], b2l[ks], t21a, 0, 0, 0);
      t21a = __builtin_amdgcn_mfma_f32_16x16x32_bf16(a1l[ks], b2h[ks], t21a, 0, 0, 0);
    }
    // stage 1: per-wave partial scores; C/D reg r = q[row=quad*4+r][d]
    float am = aam_s[d];
    #pragma unroll
    for (int r = 0; r < 4; ++r) {
      float q0 = fast_tanh(t1a[r] + t20a[r]);
      float q1 = fast_tanh(t1a[r] + t21a[r]);
      float p0 = q0 * am, p1 = q1 * am;
      #pragma unroll
      for (int m = 1; m < 16; m <<= 1) { p0 += __shfl_xor(p0, m, 64); p1 += __shfl_xor(p1, m, 64); }
      if (l15 == 0) { scw0[wv][quad * 4 + r] = p0; scw1[wv][quad * 4 + r] = p1; }
    }
    __syncthreads();
    // stage 2 (wave 0): row = l15; lane covers o = quad*16..quad*16+15 via global reloads
    if (wv == 0) {
      int row = l15, n = m0 + row;
      float s0 = scw0[0][row] + scw0[1][row] + scw0[2][row] + scw0[3][row];
      float s1 = scw1[0][row] + scw1[1][row] + scw1[2][row] + scw1[3][row];
      float mx = fmaxf(s0, s1);
      float e0 = __expf(s0 - mx), e1 = __expf(s1 - mx);
      float inv = 1.f / (e0 + e1);
      float b0 = e0 * inv, b1 = e1 * inv;
      float pc0 = 0.f, pc1 = 0.f;
      const float* px0 = x0 + n * 64 + quad * 16;
      const float* px1 = x1 + n * 64 + quad * 16;
      #pragma unroll
      for (int jj = 0; jj < 16; jj += 4) {
        float4 v0 = *(const float4*)(px0 + jj);
        float4 v1 = *(const float4*)(px1 + jj);
        float a0[4] = {v0.x, v0.y, v0.z, v0.w};
        float a1[4] = {v1.x, v1.y, v1.z, v1.w};
        #pragma unroll
        for (int c = 0; c < 4; ++c) {
          int o = quad * 16 + jj + c;
          float fv = b0 * a0[c] + b1 * a1[c];
          pc0 += fcw_s[o] * a0[c] + fcw_s[64 + o] * a1[c] + fcw_s[128 + o] * fv;
          pc1 += fcw_s[192 + o] * a0[c] + fcw_s[256 + o] * a1[c] + fcw_s[320 + o] * fv;
        }
      }
      pc0 += __shfl_xor(pc0, 16, 64); pc0 += __shfl_xor(pc0, 32, 64);
      pc1 += __shfl_xor(pc1, 16, 64); pc1 += __shfl_xor(pc1, 32, 64);
      if (lane < 16) {
        float l0 = pc0 + fcb_s[0], l1 = pc1 + fcb_s[1];
        float lm = fmaxf(l0, l1);
        float lse = lm + logf(__expf(l0 - lm) + __expf(l1 - lm));
        out[n * 2] = l0 - lse;
        out[n * 2 + 1] = l1 - lse;
      }
    }
    __syncthreads();                        // protect scw reuse next iteration
  }
}

extern "C" void kernel_launch(void* const* d_in, const int* in_sizes, int n_in,
                              void* d_out, int out_size, void* d_ws, size_t ws_size,
                              hipStream_t stream)
{
  const float* h     = (const float*)d_in[0];
  const int*   src0  = (const int*)d_in[1];
  const int*   trg0  = (const int*)d_in[2];
  const int*   src1  = (const int*)d_in[3];
  const int*   trg1  = (const int*)d_in[4];
  const float* w0    = (const float*)d_in[5];
  const float* asrc0 = (const float*)d_in[6];
  const float* atrg0 = (const float*)d_in[7];
  const float* w1    = (const float*)d_in[8];
  const float* asrc1 = (const float*)d_in[9];
  const float* atrg1 = (const float*)d_in[10];
  const float* aa_w1 = (const float*)d_in[11];
  const float* aa_w2 = (const float*)d_in[12];
  const float* aa_m  = (const float*)d_in[13];
  const float* fc_w  = (const float*)d_in[14];
  const float* fc_b  = (const float*)d_in[15];
  float* out = (float*)d_out;

  char* ws = (char*)d_ws;
  size_t off = 0;
  auto alloc = [&](size_t bytes) -> void* {
    void* p = ws + off;
    off = (off + bytes + 255) & ~(size_t)255;
    return p;
  };
  uint*  hpi      = (uint*)alloc((size_t)N_NODES * 64 * 4);     // 25.6 MB, reused per layer
  float* attn_src = (float*)alloc((size_t)N_NODES * 2 * 4);
  float* attn_trg = (float*)alloc((size_t)N_NODES * 2 * 4);
  float* x0       = (float*)alloc((size_t)N_USER * 64 * 4);     // 23 MB
  float* x1       = (float*)alloc((size_t)N_USER * 64 * 4);
  int*   count    = (int*)alloc((size_t)N_USER * 4);
  int*   offs     = (int*)alloc((size_t)(N_USER + 1) * 4);
  int*   cursor   = (int*)alloc((size_t)N_USER * 4);
  int*   aux      = (int*)alloc((size_t)NB1 * 4);
  int*   auxex    = (int*)alloc((size_t)(NB1 + 1) * 4);
  int*   csr      = (int*)alloc((size_t)N_EDGES * 4);           // 6.4 MB, reused per layer

  const int EB = (N_EDGES + 255) / 256;   // 6250
  for (int layer = 0; layer < 2; ++layer) {
    const float* w    = layer ? w1 : w0;
    const float* asrc = layer ? asrc1 : asrc0;
    const float* atrg = layer ? atrg1 : atrg0;
    const int*   src  = layer ? src1 : src0;
    const int*   trg  = layer ? trg1 : trg0;
    float*       x    = layer ? x1 : x0;
    hipLaunchKernelGGL(hp_mfma, dim3(1024), dim3(256), 0, stream,
                       h, w, asrc, atrg, hpi, attn_src, attn_trg);
    hipMemsetAsync(count, 0, (size_t)N_USER * 4, stream);
    hipLaunchKernelGGL(hist_kernel, dim3(EB), dim3(256), 0, stream, trg, count);
    hipLaunchKernelGGL(scan1_kernel, dim3(NB1), dim3(256), 0, stream, count, offs, aux);
    hipLaunchKernelGGL(scan2_kernel, dim3(1), dim3(512), 0, stream, aux, auxex);
    hipLaunchKernelGGL(scan3_kernel, dim3(NB1), dim3(256), 0, stream, offs, cursor, auxex);
    hipLaunchKernelGGL(scatter_kernel, dim3(EB), dim3(256), 0, stream, src, trg, cursor, csr);
    hipLaunchKernelGGL(accum_kernel, dim3(N_USER / 4), dim3(256), 0, stream,
                       offs, csr, attn_src, attn_trg, hpi, x);
  }
  hipLaunchKernelGGL(final_mfma, dim3(1875), dim3(256), 0, stream,
                     h, x0, x1, aa_w1, aa_w2, aa_m, fc_w, fc_b, out);
}

// Round 9
// 764.779 us; speedup vs baseline: 1.8043x; 1.1860x over previous
//
#include <hip/hip_runtime.h>
#include <hip/hip_bf16.h>
#include <math.h>

#define N_NODES 100000
#define N_EDGES 1600000
#define N_USER  90000
#define NB1     352   // ceil(N_USER/256)

typedef __attribute__((ext_vector_type(8))) short  short8;   // 8 bf16 (4 VGPRs) MFMA A/B frag
typedef __attribute__((ext_vector_type(4))) float  floatx4;  // MFMA C/D frag
typedef unsigned int  uint;
typedef unsigned short ushort;

__device__ __forceinline__ ushort f2bf(float x) {            // RNE fp32 -> bf16
  uint u = __float_as_uint(x);
  u += 0x7fffu + ((u >> 16) & 1u);
  return (ushort)(u >> 16);
}
__device__ __forceinline__ float bf2f(ushort v) { return __uint_as_float(((uint)v) << 16); }

__device__ __forceinline__ void split8(const float v[8], short8& hi, short8& lo) {
  #pragma unroll
  for (int j = 0; j < 8; ++j) {
    ushort h = f2bf(v[j]);
    hi[j] = (short)h;
    lo[j] = (short)f2bf(v[j] - bf2f(h));
  }
}
__device__ __forceinline__ void load_split8(const float* p, short8& hi, short8& lo) {
  const float4* q = (const float4*)p;
  float4 a = q[0], b = q[1];
  float v[8] = {a.x, a.y, a.z, a.w, b.x, b.y, b.z, b.w};
  split8(v, hi, lo);
}
__device__ __forceinline__ float fast_tanh(float x) {
  float t = __expf(2.f * x);
  return 1.f - 2.f / (t + 1.f);
}

// ---------------- hp via MFMA -> packed bf16, exact fp32 logits (one layer) ----------------
__global__ __launch_bounds__(256) void hp_mfma(
    const float* __restrict__ h, const float* __restrict__ w,
    const float* __restrict__ a_src, const float* __restrict__ a_trg,
    uint* __restrict__ hpi, float* __restrict__ attn_src, float* __restrict__ attn_trg)
{
  __shared__ float part[4][16][4];          // [wave][row][as0,as1,at0,at1]
  const int tid = threadIdx.x, lane = tid & 63, wv = tid >> 6;
  const int quad = lane >> 4, l15 = lane & 15;
  const int o = wv * 16 + l15;              // wave's 16-col slice of the 64 outputs
  const float vas0 = a_src[o], vas1 = a_src[64 + o];
  const float vat0 = a_trg[o], vat1 = a_trg[64 + o];
  short8 b0h[2], b0l[2], b1h[2], b1l[2];    // B frags: head0/head1 x ksteps
  #pragma unroll
  for (int ks = 0; ks < 2; ++ks) {
    float v0[8], v1[8];
    #pragma unroll
    for (int j = 0; j < 8; ++j) {
      int k = quad * 8 + j + ks * 32;       // f index
      v0[j] = w[k * 64 + o];                // w[0][f][o]
      v1[j] = w[4096 + k * 64 + o];         // w[1][f][o]
    }
    split8(v0, b0h[ks], b0l[ks]);
    split8(v1, b1h[ks], b1l[ks]);
  }
  for (int t = blockIdx.x; t < N_NODES / 16; t += gridDim.x) {
    int m0 = t * 16, arow = m0 + l15;
    short8 ah[2], al[2];
    #pragma unroll
    for (int ks = 0; ks < 2; ++ks)
      load_split8(h + arow * 64 + quad * 8 + ks * 32, ah[ks], al[ks]);
    floatx4 c0 = {0.f, 0.f, 0.f, 0.f}, c1 = {0.f, 0.f, 0.f, 0.f};
    #pragma unroll
    for (int ks = 0; ks < 2; ++ks) {
      c0 = __builtin_amdgcn_mfma_f32_16x16x32_bf16(ah[ks], b0h[ks], c0, 0, 0, 0);
      c0 = __builtin_amdgcn_mfma_f32_16x16x32_bf16(ah[ks], b0l[ks], c0, 0, 0, 0);
      c0 = __builtin_amdgcn_mfma_f32_16x16x32_bf16(al[ks], b0h[ks], c0, 0, 0, 0);
      c1 = __builtin_amdgcn_mfma_f32_16x16x32_bf16(ah[ks], b1h[ks], c1, 0, 0, 0);
      c1 = __builtin_amdgcn_mfma_f32_16x16x32_bf16(ah[ks], b1l[ks], c1, 0, 0, 0);
      c1 = __builtin_amdgcn_mfma_f32_16x16x32_bf16(al[ks], b1h[ks], c1, 0, 0, 0);
    }
    #pragma unroll
    for (int r = 0; r < 4; ++r) {
      int n = m0 + quad * 4 + r;
      hpi[n * 64 + o] = (uint)f2bf(c0[r]) | ((uint)f2bf(c1[r]) << 16);
    }
    #pragma unroll
    for (int r = 0; r < 4; ++r) {
      float pas0 = c0[r] * vas0, pas1 = c1[r] * vas1;
      float pat0 = c0[r] * vat0, pat1 = c1[r] * vat1;
      #pragma unroll
      for (int m = 1; m < 16; m <<= 1) {
        pas0 += __shfl_xor(pas0, m, 64); pas1 += __shfl_xor(pas1, m, 64);
        pat0 += __shfl_xor(pat0, m, 64); pat1 += __shfl_xor(pat1, m, 64);
      }
      if (l15 == 0) {
        part[wv][quad * 4 + r][0] = pas0; part[wv][quad * 4 + r][1] = pas1;
        part[wv][quad * 4 + r][2] = pat0; part[wv][quad * 4 + r][3] = pat1;
      }
    }
    __syncthreads();
    if (tid < 64) {
      int row = tid & 15, which = tid >> 4;
      float v = part[0][row][which] + part[1][row][which]
              + part[2][row][which] + part[3][row][which];
      int n = m0 + row;
      if (which == 0)      attn_src[n * 2]     = v;
      else if (which == 1) attn_src[n * 2 + 1] = v;
      else if (which == 2) attn_trg[n * 2]     = v;
      else                 attn_trg[n * 2 + 1] = v;
    }
    __syncthreads();
  }
}

// ---------------- CSR build (verbatim from passing R2/R7/R8) ----------------
__global__ __launch_bounds__(256) void hist_kernel(const int* __restrict__ trg, int* __restrict__ count)
{
  int e = blockIdx.x * 256 + threadIdx.x;
  if (e < N_EDGES) {
    int t = trg[e];
    if (t < N_USER) atomicAdd(&count[t], 1);
  }
}

__global__ __launch_bounds__(256) void scan1_kernel(const int* __restrict__ count,
                                                    int* __restrict__ offs, int* __restrict__ aux)
{
  __shared__ int s[256];
  int i = blockIdx.x * 256 + threadIdx.x;
  int v = (i < N_USER) ? count[i] : 0;
  s[threadIdx.x] = v;
  __syncthreads();
  for (int d = 1; d < 256; d <<= 1) {
    int t = (threadIdx.x >= d) ? s[threadIdx.x - d] : 0;
    __syncthreads();
    s[threadIdx.x] += t;
    __syncthreads();
  }
  if (i < N_USER) offs[i] = s[threadIdx.x] - v;
  if (threadIdx.x == 255) aux[blockIdx.x] = s[255];
}

__global__ __launch_bounds__(512) void scan2_kernel(const int* __restrict__ aux, int* __restrict__ auxex)
{
  __shared__ int s[512];
  int v = (threadIdx.x < NB1) ? aux[threadIdx.x] : 0;
  s[threadIdx.x] = v;
  __syncthreads();
  for (int d = 1; d < 512; d <<= 1) {
    int t = (threadIdx.x >= d) ? s[threadIdx.x - d] : 0;
    __syncthreads();
    s[threadIdx.x] += t;
    __syncthreads();
  }
  if (threadIdx.x < NB1) auxex[threadIdx.x] = s[threadIdx.x] - v;
  if (threadIdx.x == 511) auxex[NB1] = s[511];
}

__global__ __launch_bounds__(256) void scan3_kernel(int* __restrict__ offs, int* __restrict__ cursor,
                                                    const int* __restrict__ auxex)
{
  int i = blockIdx.x * 256 + threadIdx.x;
  if (i < N_USER) {
    int o = offs[i] + auxex[blockIdx.x];
    offs[i] = o;
    cursor[i] = o;
  }
  if (i == 0) offs[N_USER] = auxex[NB1];
}

__global__ __launch_bounds__(256) void scatter_kernel(const int* __restrict__ src, const int* __restrict__ trg,
                                                      int* __restrict__ cursor, int* __restrict__ csr_src)
{
  int e = blockIdx.x * 256 + threadIdx.x;
  if (e < N_EDGES) {
    int t = trg[e];
    if (t < N_USER) {
      int p = atomicAdd(&cursor[t], 1);
      csr_src[p] = src[e];
    }
  }
}

// ---------------- per-target accumulation: 4x-unrolled for memory-level parallelism ----------------
// R8 profile: 158 us, VALUBusy 39%, VGPR=12 -> latency-bound at MLP~1. Batch 4 edges'
// loads (4 csr + 4 hpi gathers + 4 attn float2) before computing -> ~4x latency overlap.
__global__ __launch_bounds__(256) void accum_kernel(
    const int* __restrict__ offs, const int* __restrict__ csr_src,
    const float* __restrict__ attn_src, const float* __restrict__ attn_trg,
    const uint* __restrict__ hpi, float* __restrict__ x)
{
  const int lane = threadIdx.x & 63, wv = threadIdx.x >> 6;
  int n = blockIdx.x * 4 + wv;
  if (n >= N_USER) return;
  int beg = max(0, offs[n]);
  int end = min(offs[n + 1], N_EDGES);
  float at0 = attn_trg[n * 2], at1 = attn_trg[n * 2 + 1];
  float acc0 = 0.f, acc1 = 0.f, den0 = 0.f, den1 = 0.f;
  const float2* att2 = (const float2*)attn_src;
  int i = beg;
  for (; i + 4 <= end; i += 4) {
    int s0 = min(max(csr_src[i], 0), N_NODES - 1);
    int s1 = min(max(csr_src[i + 1], 0), N_NODES - 1);
    int s2 = min(max(csr_src[i + 2], 0), N_NODES - 1);
    int s3 = min(max(csr_src[i + 3], 0), N_NODES - 1);
    uint p0 = hpi[s0 * 64 + lane];
    uint p1 = hpi[s1 * 64 + lane];
    uint p2 = hpi[s2 * 64 + lane];
    uint p3 = hpi[s3 * 64 + lane];
    float2 A0 = att2[s0];
    float2 A1 = att2[s1];
    float2 A2 = att2[s2];
    float2 A3 = att2[s3];
    float e00 = A0.x + at0; e00 = (e00 > 0.f) ? e00 : 0.2f * e00;
    float e01 = A0.y + at1; e01 = (e01 > 0.f) ? e01 : 0.2f * e01;
    float e10 = A1.x + at0; e10 = (e10 > 0.f) ? e10 : 0.2f * e10;
    float e11 = A1.y + at1; e11 = (e11 > 0.f) ? e11 : 0.2f * e11;
    float e20 = A2.x + at0; e20 = (e20 > 0.f) ? e20 : 0.2f * e20;
    float e21 = A2.y + at1; e21 = (e21 > 0.f) ? e21 : 0.2f * e21;
    float e30 = A3.x + at0; e30 = (e30 > 0.f) ? e30 : 0.2f * e30;
    float e31 = A3.y + at1; e31 = (e31 > 0.f) ? e31 : 0.2f * e31;
    float w00 = __expf(e00), w01 = __expf(e01);
    float w10 = __expf(e10), w11 = __expf(e11);
    float w20 = __expf(e20), w21 = __expf(e21);
    float w30 = __expf(e30), w31 = __expf(e31);
    den0 += w00 + w10 + w20 + w30;
    den1 += w01 + w11 + w21 + w31;
    acc0 += w00 * bf2f((ushort)(p0 & 0xffff)) + w10 * bf2f((ushort)(p1 & 0xffff))
          + w20 * bf2f((ushort)(p2 & 0xffff)) + w30 * bf2f((ushort)(p3 & 0xffff));
    acc1 += w01 * bf2f((ushort)(p0 >> 16)) + w11 * bf2f((ushort)(p1 >> 16))
          + w21 * bf2f((ushort)(p2 >> 16)) + w31 * bf2f((ushort)(p3 >> 16));
  }
  for (; i < end; ++i) {
    int s = min(max(csr_src[i], 0), N_NODES - 1);
    uint pv = hpi[s * 64 + lane];
    float2 A = att2[s];
    float e0 = A.x + at0; e0 = (e0 > 0.f) ? e0 : 0.2f * e0;
    float e1 = A.y + at1; e1 = (e1 > 0.f) ? e1 : 0.2f * e1;
    float w0 = __expf(e0), w1 = __expf(e1);
    den0 += w0; den1 += w1;
    acc0 += w0 * bf2f((ushort)(pv & 0xffff));
    acc1 += w1 * bf2f((ushort)(pv >> 16));
  }
  x[n * 64 + lane] = 0.5f * (acc0 / (den0 + 1e-16f) + acc1 / (den1 + 1e-16f));
}

// ---------------- final: 3 MFMA GEMMs + fused epilogue (R8-verbatim, passed) ----------------
__global__ __launch_bounds__(256) void final_mfma(
    const float* __restrict__ h, const float* __restrict__ x0, const float* __restrict__ x1,
    const float* __restrict__ aa_w1, const float* __restrict__ aa_w2, const float* __restrict__ aa_m,
    const float* __restrict__ fc_w, const float* __restrict__ fc_b, float* __restrict__ out)
{
  __shared__ float aam_s[64], fcw_s[384], fcb_s[2];
  __shared__ float scw0[4][16], scw1[4][16];   // per-wave partial scores
  const int tid = threadIdx.x;
  if (tid < 64)  aam_s[tid] = aa_m[tid];
  for (int i = tid; i < 384; i += 256) fcw_s[i] = fc_w[i];   // full coverage (R3-R6 bug fix)
  if (tid < 2)   fcb_s[tid] = fc_b[tid];
  const int lane = tid & 63, wv = tid >> 6, quad = lane >> 4, l15 = lane & 15;
  const int d = wv * 16 + l15;              // global output dim for GEMMs
  short8 b1h[2], b1l[2], b2h[2], b2l[2];    // B[k=f][n=d] = aa_w*[d*64+f]
  #pragma unroll
  for (int ks = 0; ks < 2; ++ks) {
    load_split8(aa_w1 + d * 64 + quad * 8 + ks * 32, b1h[ks], b1l[ks]);
    load_split8(aa_w2 + d * 64 + quad * 8 + ks * 32, b2h[ks], b2l[ks]);
  }
  __syncthreads();
  for (int t = blockIdx.x; t < N_USER / 16; t += gridDim.x) {
    int m0 = t * 16, arow = m0 + l15;
    short8 ahh[2], ahl[2], a0h[2], a0l[2], a1h[2], a1l[2];
    #pragma unroll
    for (int ks = 0; ks < 2; ++ks) {
      load_split8(h  + arow * 64 + quad * 8 + ks * 32, ahh[ks], ahl[ks]);
      load_split8(x0 + arow * 64 + quad * 8 + ks * 32, a0h[ks], a0l[ks]);
      load_split8(x1 + arow * 64 + quad * 8 + ks * 32, a1h[ks], a1l[ks]);
    }
    floatx4 t1a = {0.f,0.f,0.f,0.f}, t20a = {0.f,0.f,0.f,0.f}, t21a = {0.f,0.f,0.f,0.f};
    #pragma unroll
    for (int ks = 0; ks < 2; ++ks) {
      t1a  = __builtin_amdgcn_mfma_f32_16x16x32_bf16(ahh[ks], b1h[ks], t1a, 0, 0, 0);
      t1a  = __builtin_amdgcn_mfma_f32_16x16x32_bf16(ahh[ks], b1l[ks], t1a, 0, 0, 0);
      t1a  = __builtin_amdgcn_mfma_f32_16x16x32_bf16(ahl[ks], b1h[ks], t1a, 0, 0, 0);
      t20a = __builtin_amdgcn_mfma_f32_16x16x32_bf16(a0h[ks], b2h[ks], t20a, 0, 0, 0);
      t20a = __builtin_amdgcn_mfma_f32_16x16x32_bf16(a0h[ks], b2l[ks], t20a, 0, 0, 0);
      t20a = __builtin_amdgcn_mfma_f32_16x16x32_bf16(a0l[ks], b2h[ks], t20a, 0, 0, 0);
      t21a = __builtin_amdgcn_mfma_f32_16x16x32_bf16(a1h[ks], b2h[ks], t21a, 0, 0, 0);
      t21a = __builtin_amdgcn_mfma_f32_16x16x32_bf16(a1h[ks], b2l[ks], t21a, 0, 0, 0);
      t21a = __builtin_amdgcn_mfma_f32_16x16x32_bf16(a1l[ks], b2h[ks], t21a, 0, 0, 0);
    }
    float am = aam_s[d];
    #pragma unroll
    for (int r = 0; r < 4; ++r) {
      float q0 = fast_tanh(t1a[r] + t20a[r]);
      float q1 = fast_tanh(t1a[r] + t21a[r]);
      float p0 = q0 * am, p1 = q1 * am;
      #pragma unroll
      for (int m = 1; m < 16; m <<= 1) { p0 += __shfl_xor(p0, m, 64); p1 += __shfl_xor(p1, m, 64); }
      if (l15 == 0) { scw0[wv][quad * 4 + r] = p0; scw1[wv][quad * 4 + r] = p1; }
    }
    __syncthreads();
    if (wv == 0) {
      int row = l15, n = m0 + row;
      float s0 = scw0[0][row] + scw0[1][row] + scw0[2][row] + scw0[3][row];
      float s1 = scw1[0][row] + scw1[1][row] + scw1[2][row] + scw1[3][row];
      float mx = fmaxf(s0, s1);
      float e0 = __expf(s0 - mx), e1 = __expf(s1 - mx);
      float inv = 1.f / (e0 + e1);
      float b0 = e0 * inv, b1 = e1 * inv;
      float pc0 = 0.f, pc1 = 0.f;
      const float* px0 = x0 + n * 64 + quad * 16;
      const float* px1 = x1 + n * 64 + quad * 16;
      #pragma unroll
      for (int jj = 0; jj < 16; jj += 4) {
        float4 v0 = *(const float4*)(px0 + jj);
        float4 v1 = *(const float4*)(px1 + jj);
        float a0[4] = {v0.x, v0.y, v0.z, v0.w};
        float a1[4] = {v1.x, v1.y, v1.z, v1.w};
        #pragma unroll
        for (int c = 0; c < 4; ++c) {
          int o = quad * 16 + jj + c;
          float fv = b0 * a0[c] + b1 * a1[c];
          pc0 += fcw_s[o] * a0[c] + fcw_s[64 + o] * a1[c] + fcw_s[128 + o] * fv;
          pc1 += fcw_s[192 + o] * a0[c] + fcw_s[256 + o] * a1[c] + fcw_s[320 + o] * fv;
        }
      }
      pc0 += __shfl_xor(pc0, 16, 64); pc0 += __shfl_xor(pc0, 32, 64);
      pc1 += __shfl_xor(pc1, 16, 64); pc1 += __shfl_xor(pc1, 32, 64);
      if (lane < 16) {
        float l0 = pc0 + fcb_s[0], l1 = pc1 + fcb_s[1];
        float lm = fmaxf(l0, l1);
        float lse = lm + logf(__expf(l0 - lm) + __expf(l1 - lm));
        out[n * 2] = l0 - lse;
        out[n * 2 + 1] = l1 - lse;
      }
    }
    __syncthreads();
  }
}

extern "C" void kernel_launch(void* const* d_in, const int* in_sizes, int n_in,
                              void* d_out, int out_size, void* d_ws, size_t ws_size,
                              hipStream_t stream)
{
  const float* h     = (const float*)d_in[0];
  const int*   src0  = (const int*)d_in[1];
  const int*   trg0  = (const int*)d_in[2];
  const int*   src1  = (const int*)d_in[3];
  const int*   trg1  = (const int*)d_in[4];
  const float* w0    = (const float*)d_in[5];
  const float* asrc0 = (const float*)d_in[6];
  const float* atrg0 = (const float*)d_in[7];
  const float* w1    = (const float*)d_in[8];
  const float* asrc1 = (const float*)d_in[9];
  const float* atrg1 = (const float*)d_in[10];
  const float* aa_w1 = (const float*)d_in[11];
  const float* aa_w2 = (const float*)d_in[12];
  const float* aa_m  = (const float*)d_in[13];
  const float* fc_w  = (const float*)d_in[14];
  const float* fc_b  = (const float*)d_in[15];
  float* out = (float*)d_out;

  char* ws = (char*)d_ws;
  size_t off = 0;
  auto alloc = [&](size_t bytes) -> void* {
    void* p = ws + off;
    off = (off + bytes + 255) & ~(size_t)255;
    return p;
  };
  uint*  hpi      = (uint*)alloc((size_t)N_NODES * 64 * 4);     // 25.6 MB, reused per layer
  float* attn_src = (float*)alloc((size_t)N_NODES * 2 * 4);
  float* attn_trg = (float*)alloc((size_t)N_NODES * 2 * 4);
  float* x0       = (float*)alloc((size_t)N_USER * 64 * 4);     // 23 MB
  float* x1       = (float*)alloc((size_t)N_USER * 64 * 4);
  int*   count    = (int*)alloc((size_t)N_USER * 4);
  int*   offs     = (int*)alloc((size_t)(N_USER + 1) * 4);
  int*   cursor   = (int*)alloc((size_t)N_USER * 4);
  int*   aux      = (int*)alloc((size_t)NB1 * 4);
  int*   auxex    = (int*)alloc((size_t)(NB1 + 1) * 4);
  int*   csr      = (int*)alloc((size_t)N_EDGES * 4);           // 6.4 MB, reused per layer

  const int EB = (N_EDGES + 255) / 256;   // 6250
  for (int layer = 0; layer < 2; ++layer) {
    const float* w    = layer ? w1 : w0;
    const float* asrc = layer ? asrc1 : asrc0;
    const float* atrg = layer ? atrg1 : atrg0;
    const int*   src  = layer ? src1 : src0;
    const int*   trg  = layer ? trg1 : trg0;
    float*       x    = layer ? x1 : x0;
    hipLaunchKernelGGL(hp_mfma, dim3(1024), dim3(256), 0, stream,
                       h, w, asrc, atrg, hpi, attn_src, attn_trg);
    hipMemsetAsync(count, 0, (size_t)N_USER * 4, stream);
    hipLaunchKernelGGL(hist_kernel, dim3(EB), dim3(256), 0, stream, trg, count);
    hipLaunchKernelGGL(scan1_kernel, dim3(NB1), dim3(256), 0, stream, count, offs, aux);
    hipLaunchKernelGGL(scan2_kernel, dim3(1), dim3(512), 0, stream, aux, auxex);
    hipLaunchKernelGGL(scan3_kernel, dim3(NB1), dim3(256), 0, stream, offs, cursor, auxex);
    hipLaunchKernelGGL(scatter_kernel, dim3(EB), dim3(256), 0, stream, src, trg, cursor, csr);
    hipLaunchKernelGGL(accum_kernel, dim3(N_USER / 4), dim3(256), 0, stream,
                       offs, csr, attn_src, attn_trg, hpi, x);
  }
  hipLaunchKernelGGL(final_mfma, dim3(1875), dim3(256), 0, stream,
                     h, x0, x1, aa_w1, aa_w2, aa_m, fc_w, fc_b, out);
}

// Round 10
// 638.249 us; speedup vs baseline: 2.1620x; 1.1982x over previous
//
#include <hip/hip_runtime.h>
#include <hip/hip_bf16.h>
#include <math.h>

#define N_NODES 100000
#define N_EDGES 1600000
#define N_USER  90000
#define NB1     352   // ceil(N_USER/256)
#define NBUCK   256
#define BSZ     352   // targets per bucket; 256*352 = 90112 >= N_USER
#define TILE    2048  // edges per bucket_kernel block

typedef __attribute__((ext_vector_type(8))) short  short8;   // 8 bf16 (4 VGPRs) MFMA A/B frag
typedef __attribute__((ext_vector_type(4))) float  floatx4;  // MFMA C/D frag
typedef unsigned int  uint;
typedef unsigned short ushort;

__device__ __forceinline__ ushort f2bf(float x) {            // RNE fp32 -> bf16
  uint u = __float_as_uint(x);
  u += 0x7fffu + ((u >> 16) & 1u);
  return (ushort)(u >> 16);
}
__device__ __forceinline__ float bf2f(ushort v) { return __uint_as_float(((uint)v) << 16); }

__device__ __forceinline__ void split8(const float v[8], short8& hi, short8& lo) {
  #pragma unroll
  for (int j = 0; j < 8; ++j) {
    ushort h = f2bf(v[j]);
    hi[j] = (short)h;
    lo[j] = (short)f2bf(v[j] - bf2f(h));
  }
}
__device__ __forceinline__ void load_split8(const float* p, short8& hi, short8& lo) {
  const float4* q = (const float4*)p;
  float4 a = q[0], b = q[1];
  float v[8] = {a.x, a.y, a.z, a.w, b.x, b.y, b.z, b.w};
  split8(v, hi, lo);
}
__device__ __forceinline__ float fast_tanh(float x) {
  float t = __expf(2.f * x);
  return 1.f - 2.f / (t + 1.f);
}

// ---------------- hp via MFMA -> packed bf16, exact fp32 logits (one layer) ----------------
__global__ __launch_bounds__(256) void hp_mfma(
    const float* __restrict__ h, const float* __restrict__ w,
    const float* __restrict__ a_src, const float* __restrict__ a_trg,
    uint* __restrict__ hpi, float* __restrict__ attn_src, float* __restrict__ attn_trg)
{
  __shared__ float part[4][16][4];          // [wave][row][as0,as1,at0,at1]
  const int tid = threadIdx.x, lane = tid & 63, wv = tid >> 6;
  const int quad = lane >> 4, l15 = lane & 15;
  const int o = wv * 16 + l15;              // wave's 16-col slice of the 64 outputs
  const float vas0 = a_src[o], vas1 = a_src[64 + o];
  const float vat0 = a_trg[o], vat1 = a_trg[64 + o];
  short8 b0h[2], b0l[2], b1h[2], b1l[2];    // B frags: head0/head1 x ksteps
  #pragma unroll
  for (int ks = 0; ks < 2; ++ks) {
    float v0[8], v1[8];
    #pragma unroll
    for (int j = 0; j < 8; ++j) {
      int k = quad * 8 + j + ks * 32;       // f index
      v0[j] = w[k * 64 + o];                // w[0][f][o]
      v1[j] = w[4096 + k * 64 + o];         // w[1][f][o]
    }
    split8(v0, b0h[ks], b0l[ks]);
    split8(v1, b1h[ks], b1l[ks]);
  }
  for (int t = blockIdx.x; t < N_NODES / 16; t += gridDim.x) {
    int m0 = t * 16, arow = m0 + l15;
    short8 ah[2], al[2];
    #pragma unroll
    for (int ks = 0; ks < 2; ++ks)
      load_split8(h + arow * 64 + quad * 8 + ks * 32, ah[ks], al[ks]);
    floatx4 c0 = {0.f, 0.f, 0.f, 0.f}, c1 = {0.f, 0.f, 0.f, 0.f};
    #pragma unroll
    for (int ks = 0; ks < 2; ++ks) {
      c0 = __builtin_amdgcn_mfma_f32_16x16x32_bf16(ah[ks], b0h[ks], c0, 0, 0, 0);
      c0 = __builtin_amdgcn_mfma_f32_16x16x32_bf16(ah[ks], b0l[ks], c0, 0, 0, 0);
      c0 = __builtin_amdgcn_mfma_f32_16x16x32_bf16(al[ks], b0h[ks], c0, 0, 0, 0);
      c1 = __builtin_amdgcn_mfma_f32_16x16x32_bf16(ah[ks], b1h[ks], c1, 0, 0, 0);
      c1 = __builtin_amdgcn_mfma_f32_16x16x32_bf16(ah[ks], b1l[ks], c1, 0, 0, 0);
      c1 = __builtin_amdgcn_mfma_f32_16x16x32_bf16(al[ks], b1h[ks], c1, 0, 0, 0);
    }
    #pragma unroll
    for (int r = 0; r < 4; ++r) {
      int n = m0 + quad * 4 + r;
      hpi[n * 64 + o] = (uint)f2bf(c0[r]) | ((uint)f2bf(c1[r]) << 16);
    }
    #pragma unroll
    for (int r = 0; r < 4; ++r) {
      float pas0 = c0[r] * vas0, pas1 = c1[r] * vas1;
      float pat0 = c0[r] * vat0, pat1 = c1[r] * vat1;
      #pragma unroll
      for (int m = 1; m < 16; m <<= 1) {
        pas0 += __shfl_xor(pas0, m, 64); pas1 += __shfl_xor(pas1, m, 64);
        pat0 += __shfl_xor(pat0, m, 64); pat1 += __shfl_xor(pat1, m, 64);
      }
      if (l15 == 0) {
        part[wv][quad * 4 + r][0] = pas0; part[wv][quad * 4 + r][1] = pas1;
        part[wv][quad * 4 + r][2] = pat0; part[wv][quad * 4 + r][3] = pat1;
      }
    }
    __syncthreads();
    if (tid < 64) {
      int row = tid & 15, which = tid >> 4;
      float v = part[0][row][which] + part[1][row][which]
              + part[2][row][which] + part[3][row][which];
      int n = m0 + row;
      if (which == 0)      attn_src[n * 2]     = v;
      else if (which == 1) attn_src[n * 2 + 1] = v;
      else if (which == 2) attn_trg[n * 2]     = v;
      else                 attn_trg[n * 2 + 1] = v;
    }
    __syncthreads();
  }
}

// ---------------- CSR build: hist + scans (verbatim), then bucketed 2-level scatter ----------------
__global__ __launch_bounds__(256) void hist_kernel(const int* __restrict__ trg, int* __restrict__ count)
{
  int e = blockIdx.x * 256 + threadIdx.x;
  if (e < N_EDGES) {
    int t = trg[e];
    if (t < N_USER) atomicAdd(&count[t], 1);
  }
}

__global__ __launch_bounds__(256) void scan1_kernel(const int* __restrict__ count,
                                                    int* __restrict__ offs, int* __restrict__ aux)
{
  __shared__ int s[256];
  int i = blockIdx.x * 256 + threadIdx.x;
  int v = (i < N_USER) ? count[i] : 0;
  s[threadIdx.x] = v;
  __syncthreads();
  for (int d = 1; d < 256; d <<= 1) {
    int t = (threadIdx.x >= d) ? s[threadIdx.x - d] : 0;
    __syncthreads();
    s[threadIdx.x] += t;
    __syncthreads();
  }
  if (i < N_USER) offs[i] = s[threadIdx.x] - v;
  if (threadIdx.x == 255) aux[blockIdx.x] = s[255];
}

__global__ __launch_bounds__(512) void scan2_kernel(const int* __restrict__ aux, int* __restrict__ auxex)
{
  __shared__ int s[512];
  int v = (threadIdx.x < NB1) ? aux[threadIdx.x] : 0;
  s[threadIdx.x] = v;
  __syncthreads();
  for (int d = 1; d < 512; d <<= 1) {
    int t = (threadIdx.x >= d) ? s[threadIdx.x - d] : 0;
    __syncthreads();
    s[threadIdx.x] += t;
    __syncthreads();
  }
  if (threadIdx.x < NB1) auxex[threadIdx.x] = s[threadIdx.x] - v;
  if (threadIdx.x == 511) auxex[NB1] = s[511];
}

// scan3 also seeds the (64B-padded) bucket cursors: bucket b starts at offs[b*BSZ].
__global__ __launch_bounds__(256) void scan3_kernel(int* __restrict__ offs, int* __restrict__ cursor,
                                                    const int* __restrict__ auxex, int* __restrict__ bcur)
{
  int i = blockIdx.x * 256 + threadIdx.x;
  if (i < N_USER) {
    int o = offs[i] + auxex[blockIdx.x];
    offs[i] = o;
    cursor[i] = o;
    if ((i % BSZ) == 0) bcur[(i / BSZ) * 16] = o;   // 16-int stride = 1 line/bucket
  }
  if (i == 0) offs[N_USER] = auxex[NB1];
}

// Pass B: bin a 2048-edge tile by bucket in LDS, bulk-append contiguous runs per bucket.
// Converts 1.6M random 4B scatters into ~64B coalesced chunk writes (R9: 96MB HBM WRITE for
// a 6.4MB payload = cross-XCD partial-line amplification; this kills it).
__global__ __launch_bounds__(256) void bucket_kernel(
    const int* __restrict__ src, const int* __restrict__ trg,
    int* __restrict__ bcur, uint2* __restrict__ pairbuf)
{
  __shared__ uint2 plds[TILE];
  __shared__ int bcnt[NBUCK], bscan[NBUCK], gbase[NBUCK];
  const int tid = threadIdx.x;
  const int base = blockIdx.x * TILE;
  bcnt[tid] = 0;
  __syncthreads();
  int myb[8], myr[8];
  uint2 myp[8];
  #pragma unroll
  for (int j = 0; j < 8; ++j) {
    int e = base + j * 256 + tid;
    myb[j] = -1;
    if (e < N_EDGES) {
      int t = trg[e];
      if (t < N_USER) {
        int b = t / BSZ;
        myb[j] = b;
        myr[j] = atomicAdd(&bcnt[b], 1);
        myp[j].x = (uint)src[e];
        myp[j].y = (uint)t;
      }
    }
  }
  __syncthreads();
  gbase[tid] = atomicAdd(&bcur[tid * 16], bcnt[tid]);
  bscan[tid] = bcnt[tid];
  __syncthreads();
  for (int d = 1; d < 256; d <<= 1) {
    int v = (tid >= d) ? bscan[tid - d] : 0;
    __syncthreads();
    bscan[tid] += v;
    __syncthreads();
  }
  #pragma unroll
  for (int j = 0; j < 8; ++j)
    if (myb[j] >= 0) plds[bscan[myb[j]] - bcnt[myb[j]] + myr[j]] = myp[j];
  __syncthreads();
  int total = bscan[NBUCK - 1];
  for (int i = tid; i < total; i += 256) {
    uint2 pr = plds[i];
    int b = (int)pr.y / BSZ;
    int idx = gbase[b] + (i - (bscan[b] - bcnt[b]));
    if (idx >= 0 && idx < N_EDGES) pairbuf[idx] = pr;
  }
}

// Pass C: one block per bucket; per-target atomic scatter with full L2 locality
// (cursor lines + csr region of a bucket are touched by exactly one block).
__global__ __launch_bounds__(256) void fine_kernel(
    const uint2* __restrict__ pairbuf, const int* __restrict__ offs,
    int* __restrict__ cursor, int* __restrict__ csr_src)
{
  const int b = blockIdx.x;
  int t0 = b * BSZ, t1 = min(t0 + BSZ, N_USER);
  int pbeg = max(0, offs[t0]);
  int pend = min(offs[t1], N_EDGES);
  for (int i = pbeg + threadIdx.x; i < pend; i += 256) {
    uint2 pr = pairbuf[i];
    int t = min((int)pr.y, N_USER - 1);
    int p = atomicAdd(&cursor[t], 1);
    p = min(max(p, 0), N_EDGES - 1);
    csr_src[p] = (int)pr.x;
  }
}

// ---------------- per-target accumulation: 4x-unrolled MLP (R9-verbatim, passed) ----------------
__global__ __launch_bounds__(256) void accum_kernel(
    const int* __restrict__ offs, const int* __restrict__ csr_src,
    const float* __restrict__ attn_src, const float* __restrict__ attn_trg,
    const uint* __restrict__ hpi, float* __restrict__ x)
{
  const int lane = threadIdx.x & 63, wv = threadIdx.x >> 6;
  int n = blockIdx.x * 4 + wv;
  if (n >= N_USER) return;
  int beg = max(0, offs[n]);
  int end = min(offs[n + 1], N_EDGES);
  float at0 = attn_trg[n * 2], at1 = attn_trg[n * 2 + 1];
  float acc0 = 0.f, acc1 = 0.f, den0 = 0.f, den1 = 0.f;
  const float2* att2 = (const float2*)attn_src;
  int i = beg;
  for (; i + 4 <= end; i += 4) {
    int s0 = min(max(csr_src[i], 0), N_NODES - 1);
    int s1 = min(max(csr_src[i + 1], 0), N_NODES - 1);
    int s2 = min(max(csr_src[i + 2], 0), N_NODES - 1);
    int s3 = min(max(csr_src[i + 3], 0), N_NODES - 1);
    uint p0 = hpi[s0 * 64 + lane];
    uint p1 = hpi[s1 * 64 + lane];
    uint p2 = hpi[s2 * 64 + lane];
    uint p3 = hpi[s3 * 64 + lane];
    float2 A0 = att2[s0];
    float2 A1 = att2[s1];
    float2 A2 = att2[s2];
    float2 A3 = att2[s3];
    float e00 = A0.x + at0; e00 = (e00 > 0.f) ? e00 : 0.2f * e00;
    float e01 = A0.y + at1; e01 = (e01 > 0.f) ? e01 : 0.2f * e01;
    float e10 = A1.x + at0; e10 = (e10 > 0.f) ? e10 : 0.2f * e10;
    float e11 = A1.y + at1; e11 = (e11 > 0.f) ? e11 : 0.2f * e11;
    float e20 = A2.x + at0; e20 = (e20 > 0.f) ? e20 : 0.2f * e20;
    float e21 = A2.y + at1; e21 = (e21 > 0.f) ? e21 : 0.2f * e21;
    float e30 = A3.x + at0; e30 = (e30 > 0.f) ? e30 : 0.2f * e30;
    float e31 = A3.y + at1; e31 = (e31 > 0.f) ? e31 : 0.2f * e31;
    float w00 = __expf(e00), w01 = __expf(e01);
    float w10 = __expf(e10), w11 = __expf(e11);
    float w20 = __expf(e20), w21 = __expf(e21);
    float w30 = __expf(e30), w31 = __expf(e31);
    den0 += w00 + w10 + w20 + w30;
    den1 += w01 + w11 + w21 + w31;
    acc0 += w00 * bf2f((ushort)(p0 & 0xffff)) + w10 * bf2f((ushort)(p1 & 0xffff))
          + w20 * bf2f((ushort)(p2 & 0xffff)) + w30 * bf2f((ushort)(p3 & 0xffff));
    acc1 += w01 * bf2f((ushort)(p0 >> 16)) + w11 * bf2f((ushort)(p1 >> 16))
          + w21 * bf2f((ushort)(p2 >> 16)) + w31 * bf2f((ushort)(p3 >> 16));
  }
  for (; i < end; ++i) {
    int s = min(max(csr_src[i], 0), N_NODES - 1);
    uint pv = hpi[s * 64 + lane];
    float2 A = att2[s];
    float e0 = A.x + at0; e0 = (e0 > 0.f) ? e0 : 0.2f * e0;
    float e1 = A.y + at1; e1 = (e1 > 0.f) ? e1 : 0.2f * e1;
    float w0 = __expf(e0), w1 = __expf(e1);
    den0 += w0; den1 += w1;
    acc0 += w0 * bf2f((ushort)(pv & 0xffff));
    acc1 += w1 * bf2f((ushort)(pv >> 16));
  }
  x[n * 64 + lane] = 0.5f * (acc0 / (den0 + 1e-16f) + acc1 / (den1 + 1e-16f));
}

// ---------------- final: 3 MFMA GEMMs + fused epilogue (R8/R9-verbatim, passed) ----------------
__global__ __launch_bounds__(256) void final_mfma(
    const float* __restrict__ h, const float* __restrict__ x0, const float* __restrict__ x1,
    const float* __restrict__ aa_w1, const float* __restrict__ aa_w2, const float* __restrict__ aa_m,
    const float* __restrict__ fc_w, const float* __restrict__ fc_b, float* __restrict__ out)
{
  __shared__ float aam_s[64], fcw_s[384], fcb_s[2];
  __shared__ float scw0[4][16], scw1[4][16];
  const int tid = threadIdx.x;
  if (tid < 64)  aam_s[tid] = aa_m[tid];
  for (int i = tid; i < 384; i += 256) fcw_s[i] = fc_w[i];
  if (tid < 2)   fcb_s[tid] = fc_b[tid];
  const int lane = tid & 63, wv = tid >> 6, quad = lane >> 4, l15 = lane & 15;
  const int d = wv * 16 + l15;
  short8 b1h[2], b1l[2], b2h[2], b2l[2];
  #pragma unroll
  for (int ks = 0; ks < 2; ++ks) {
    load_split8(aa_w1 + d * 64 + quad * 8 + ks * 32, b1h[ks], b1l[ks]);
    load_split8(aa_w2 + d * 64 + quad * 8 + ks * 32, b2h[ks], b2l[ks]);
  }
  __syncthreads();
  for (int t = blockIdx.x; t < N_USER / 16; t += gridDim.x) {
    int m0 = t * 16, arow = m0 + l15;
    short8 ahh[2], ahl[2], a0h[2], a0l[2], a1h[2], a1l[2];
    #pragma unroll
    for (int ks = 0; ks < 2; ++ks) {
      load_split8(h  + arow * 64 + quad * 8 + ks * 32, ahh[ks], ahl[ks]);
      load_split8(x0 + arow * 64 + quad * 8 + ks * 32, a0h[ks], a0l[ks]);
      load_split8(x1 + arow * 64 + quad * 8 + ks * 32, a1h[ks], a1l[ks]);
    }
    floatx4 t1a = {0.f,0.f,0.f,0.f}, t20a = {0.f,0.f,0.f,0.f}, t21a = {0.f,0.f,0.f,0.f};
    #pragma unroll
    for (int ks = 0; ks < 2; ++ks) {
      t1a  = __builtin_amdgcn_mfma_f32_16x16x32_bf16(ahh[ks], b1h[ks], t1a, 0, 0, 0);
      t1a  = __builtin_amdgcn_mfma_f32_16x16x32_bf16(ahh[ks], b1l[ks], t1a, 0, 0, 0);
      t1a  = __builtin_amdgcn_mfma_f32_16x16x32_bf16(ahl[ks], b1h[ks], t1a, 0, 0, 0);
      t20a = __builtin_amdgcn_mfma_f32_16x16x32_bf16(a0h[ks], b2h[ks], t20a, 0, 0, 0);
      t20a = __builtin_amdgcn_mfma_f32_16x16x32_bf16(a0h[ks], b2l[ks], t20a, 0, 0, 0);
      t20a = __builtin_amdgcn_mfma_f32_16x16x32_bf16(a0l[ks], b2h[ks], t20a, 0, 0, 0);
      t21a = __builtin_amdgcn_mfma_f32_16x16x32_bf16(a1h[ks], b2h[ks], t21a, 0, 0, 0);
      t21a = __builtin_amdgcn_mfma_f32_16x16x32_bf16(a1h[ks], b2l[ks], t21a, 0, 0, 0);
      t21a = __builtin_amdgcn_mfma_f32_16x16x32_bf16(a1l[ks], b2h[ks], t21a, 0, 0, 0);
    }
    float am = aam_s[d];
    #pragma unroll
    for (int r = 0; r < 4; ++r) {
      float q0 = fast_tanh(t1a[r] + t20a[r]);
      float q1 = fast_tanh(t1a[r] + t21a[r]);
      float p0 = q0 * am, p1 = q1 * am;
      #pragma unroll
      for (int m = 1; m < 16; m <<= 1) { p0 += __shfl_xor(p0, m, 64); p1 += __shfl_xor(p1, m, 64); }
      if (l15 == 0) { scw0[wv][quad * 4 + r] = p0; scw1[wv][quad * 4 + r] = p1; }
    }
    __syncthreads();
    if (wv == 0) {
      int row = l15, n = m0 + row;
      float s0 = scw0[0][row] + scw0[1][row] + scw0[2][row] + scw0[3][row];
      float s1 = scw1[0][row] + scw1[1][row] + scw1[2][row] + scw1[3][row];
      float mx = fmaxf(s0, s1);
      float e0 = __expf(s0 - mx), e1 = __expf(s1 - mx);
      float inv = 1.f / (e0 + e1);
      float b0 = e0 * inv, b1 = e1 * inv;
      float pc0 = 0.f, pc1 = 0.f;
      const float* px0 = x0 + n * 64 + quad * 16;
      const float* px1 = x1 + n * 64 + quad * 16;
      #pragma unroll
      for (int jj = 0; jj < 16; jj += 4) {
        float4 v0 = *(const float4*)(px0 + jj);
        float4 v1 = *(const float4*)(px1 + jj);
        float a0[4] = {v0.x, v0.y, v0.z, v0.w};
        float a1[4] = {v1.x, v1.y, v1.z, v1.w};
        #pragma unroll
        for (int c = 0; c < 4; ++c) {
          int o = quad * 16 + jj + c;
          float fv = b0 * a0[c] + b1 * a1[c];
          pc0 += fcw_s[o] * a0[c] + fcw_s[64 + o] * a1[c] + fcw_s[128 + o] * fv;
          pc1 += fcw_s[192 + o] * a0[c] + fcw_s[256 + o] * a1[c] + fcw_s[320 + o] * fv;
        }
      }
      pc0 += __shfl_xor(pc0, 16, 64); pc0 += __shfl_xor(pc0, 32, 64);
      pc1 += __shfl_xor(pc1, 16, 64); pc1 += __shfl_xor(pc1, 32, 64);
      if (lane < 16) {
        float l0 = pc0 + fcb_s[0], l1 = pc1 + fcb_s[1];
        float lm = fmaxf(l0, l1);
        float lse = lm + logf(__expf(l0 - lm) + __expf(l1 - lm));
        out[n * 2] = l0 - lse;
        out[n * 2 + 1] = l1 - lse;
      }
    }
    __syncthreads();
  }
}

extern "C" void kernel_launch(void* const* d_in, const int* in_sizes, int n_in,
                              void* d_out, int out_size, void* d_ws, size_t ws_size,
                              hipStream_t stream)
{
  const float* h     = (const float*)d_in[0];
  const int*   src0  = (const int*)d_in[1];
  const int*   trg0  = (const int*)d_in[2];
  const int*   src1  = (const int*)d_in[3];
  const int*   trg1  = (const int*)d_in[4];
  const float* w0    = (const float*)d_in[5];
  const float* asrc0 = (const float*)d_in[6];
  const float* atrg0 = (const float*)d_in[7];
  const float* w1    = (const float*)d_in[8];
  const float* asrc1 = (const float*)d_in[9];
  const float* atrg1 = (const float*)d_in[10];
  const float* aa_w1 = (const float*)d_in[11];
  const float* aa_w2 = (const float*)d_in[12];
  const float* aa_m  = (const float*)d_in[13];
  const float* fc_w  = (const float*)d_in[14];
  const float* fc_b  = (const float*)d_in[15];
  float* out = (float*)d_out;

  char* ws = (char*)d_ws;
  size_t off = 0;
  auto alloc = [&](size_t bytes) -> void* {
    void* p = ws + off;
    off = (off + bytes + 255) & ~(size_t)255;
    return p;
  };
  // total ~93 MB (< R2/R7 proven 106 MB)
  uint*  hpi      = (uint*)alloc((size_t)N_NODES * 64 * 4);     // 25.6 MB, reused per layer
  float* attn_src = (float*)alloc((size_t)N_NODES * 2 * 4);
  float* attn_trg = (float*)alloc((size_t)N_NODES * 2 * 4);
  float* x0       = (float*)alloc((size_t)N_USER * 64 * 4);     // 23 MB
  float* x1       = (float*)alloc((size_t)N_USER * 64 * 4);
  int*   count    = (int*)alloc((size_t)N_USER * 4);
  int*   offs     = (int*)alloc((size_t)(N_USER + 1) * 4);
  int*   cursor   = (int*)alloc((size_t)N_USER * 4);
  int*   aux      = (int*)alloc((size_t)NB1 * 4);
  int*   auxex    = (int*)alloc((size_t)(NB1 + 1) * 4);
  int*   csr      = (int*)alloc((size_t)N_EDGES * 4);           // 6.4 MB, reused per layer
  uint2* pairbuf  = (uint2*)alloc((size_t)N_EDGES * 8);         // 12.8 MB, reused per layer
  int*   bcur     = (int*)alloc((size_t)NBUCK * 16 * 4);        // padded bucket cursors

  const int EB = (N_EDGES + 255) / 256;      // 6250
  const int TB = (N_EDGES + TILE - 1) / TILE;// 782
  for (int layer = 0; layer < 2; ++layer) {
    const float* w    = layer ? w1 : w0;
    const float* asrc = layer ? asrc1 : asrc0;
    const float* atrg = layer ? atrg1 : atrg0;
    const int*   src  = layer ? src1 : src0;
    const int*   trg  = layer ? trg1 : trg0;
    float*       x    = layer ? x1 : x0;
    hipLaunchKernelGGL(hp_mfma, dim3(1024), dim3(256), 0, stream,
                       h, w, asrc, atrg, hpi, attn_src, attn_trg);
    hipMemsetAsync(count, 0, (size_t)N_USER * 4, stream);
    hipLaunchKernelGGL(hist_kernel, dim3(EB), dim3(256), 0, stream, trg, count);
    hipLaunchKernelGGL(scan1_kernel, dim3(NB1), dim3(256), 0, stream, count, offs, aux);
    hipLaunchKernelGGL(scan2_kernel, dim3(1), dim3(512), 0, stream, aux, auxex);
    hipLaunchKernelGGL(scan3_kernel, dim3(NB1), dim3(256), 0, stream, offs, cursor, auxex, bcur);
    hipLaunchKernelGGL(bucket_kernel, dim3(TB), dim3(256), 0, stream, src, trg, bcur, pairbuf);
    hipLaunchKernelGGL(fine_kernel, dim3(NBUCK), dim3(256), 0, stream, pairbuf, offs, cursor, csr);
    hipLaunchKernelGGL(accum_kernel, dim3(N_USER / 4), dim3(256), 0, stream,
                       offs, csr, attn_src, attn_trg, hpi, x);
  }
  hipLaunchKernelGGL(final_mfma, dim3(1875), dim3(256), 0, stream,
                     h, x0, x1, aa_w1, aa_w2, aa_m, fc_w, fc_b, out);
}

// Round 11
// 631.924 us; speedup vs baseline: 2.1837x; 1.0100x over previous
//
#include <hip/hip_runtime.h>
#include <hip/hip_bf16.h>
#include <math.h>

#define N_NODES 100000
#define N_EDGES 1600000
#define N_USER  90000
#define NB1     352   // ceil(N_USER/256)
#define NBUCK   256
#define BSZ     352   // targets per bucket; 256*352 = 90112 >= N_USER
#define TILE    2048  // edges per bucket_kernel block

typedef __attribute__((ext_vector_type(8))) short  short8;   // 8 bf16 (4 VGPRs) MFMA A/B frag
typedef __attribute__((ext_vector_type(4))) float  floatx4;  // MFMA C/D frag
typedef unsigned int  uint;
typedef unsigned short ushort;

__device__ __forceinline__ ushort f2bf(float x) {            // RNE fp32 -> bf16
  uint u = __float_as_uint(x);
  u += 0x7fffu + ((u >> 16) & 1u);
  return (ushort)(u >> 16);
}
__device__ __forceinline__ float bf2f(ushort v) { return __uint_as_float(((uint)v) << 16); }

__device__ __forceinline__ void split8(const float v[8], short8& hi, short8& lo) {
  #pragma unroll
  for (int j = 0; j < 8; ++j) {
    ushort h = f2bf(v[j]);
    hi[j] = (short)h;
    lo[j] = (short)f2bf(v[j] - bf2f(h));
  }
}
__device__ __forceinline__ void load_split8(const float* p, short8& hi, short8& lo) {
  const float4* q = (const float4*)p;
  float4 a = q[0], b = q[1];
  float v[8] = {a.x, a.y, a.z, a.w, b.x, b.y, b.z, b.w};
  split8(v, hi, lo);
}
__device__ __forceinline__ float fast_tanh(float x) {
  float t = __expf(2.f * x);
  return 1.f - 2.f / (t + 1.f);
}

// ---------------- hp via MFMA -> packed bf16, exact fp32 logits (one layer) ----------------
__global__ __launch_bounds__(256) void hp_mfma(
    const float* __restrict__ h, const float* __restrict__ w,
    const float* __restrict__ a_src, const float* __restrict__ a_trg,
    uint* __restrict__ hpi, float* __restrict__ attn_src, float* __restrict__ attn_trg)
{
  __shared__ float part[4][16][4];          // [wave][row][as0,as1,at0,at1]
  const int tid = threadIdx.x, lane = tid & 63, wv = tid >> 6;
  const int quad = lane >> 4, l15 = lane & 15;
  const int o = wv * 16 + l15;              // wave's 16-col slice of the 64 outputs
  const float vas0 = a_src[o], vas1 = a_src[64 + o];
  const float vat0 = a_trg[o], vat1 = a_trg[64 + o];
  short8 b0h[2], b0l[2], b1h[2], b1l[2];    // B frags: head0/head1 x ksteps
  #pragma unroll
  for (int ks = 0; ks < 2; ++ks) {
    float v0[8], v1[8];
    #pragma unroll
    for (int j = 0; j < 8; ++j) {
      int k = quad * 8 + j + ks * 32;       // f index
      v0[j] = w[k * 64 + o];                // w[0][f][o]
      v1[j] = w[4096 + k * 64 + o];         // w[1][f][o]
    }
    split8(v0, b0h[ks], b0l[ks]);
    split8(v1, b1h[ks], b1l[ks]);
  }
  for (int t = blockIdx.x; t < N_NODES / 16; t += gridDim.x) {
    int m0 = t * 16, arow = m0 + l15;
    short8 ah[2], al[2];
    #pragma unroll
    for (int ks = 0; ks < 2; ++ks)
      load_split8(h + arow * 64 + quad * 8 + ks * 32, ah[ks], al[ks]);
    floatx4 c0 = {0.f, 0.f, 0.f, 0.f}, c1 = {0.f, 0.f, 0.f, 0.f};
    #pragma unroll
    for (int ks = 0; ks < 2; ++ks) {
      c0 = __builtin_amdgcn_mfma_f32_16x16x32_bf16(ah[ks], b0h[ks], c0, 0, 0, 0);
      c0 = __builtin_amdgcn_mfma_f32_16x16x32_bf16(ah[ks], b0l[ks], c0, 0, 0, 0);
      c0 = __builtin_amdgcn_mfma_f32_16x16x32_bf16(al[ks], b0h[ks], c0, 0, 0, 0);
      c1 = __builtin_amdgcn_mfma_f32_16x16x32_bf16(ah[ks], b1h[ks], c1, 0, 0, 0);
      c1 = __builtin_amdgcn_mfma_f32_16x16x32_bf16(ah[ks], b1l[ks], c1, 0, 0, 0);
      c1 = __builtin_amdgcn_mfma_f32_16x16x32_bf16(al[ks], b1h[ks], c1, 0, 0, 0);
    }
    #pragma unroll
    for (int r = 0; r < 4; ++r) {
      int n = m0 + quad * 4 + r;
      hpi[n * 64 + o] = (uint)f2bf(c0[r]) | ((uint)f2bf(c1[r]) << 16);
    }
    #pragma unroll
    for (int r = 0; r < 4; ++r) {
      float pas0 = c0[r] * vas0, pas1 = c1[r] * vas1;
      float pat0 = c0[r] * vat0, pat1 = c1[r] * vat1;
      #pragma unroll
      for (int m = 1; m < 16; m <<= 1) {
        pas0 += __shfl_xor(pas0, m, 64); pas1 += __shfl_xor(pas1, m, 64);
        pat0 += __shfl_xor(pat0, m, 64); pat1 += __shfl_xor(pat1, m, 64);
      }
      if (l15 == 0) {
        part[wv][quad * 4 + r][0] = pas0; part[wv][quad * 4 + r][1] = pas1;
        part[wv][quad * 4 + r][2] = pat0; part[wv][quad * 4 + r][3] = pat1;
      }
    }
    __syncthreads();
    if (tid < 64) {
      int row = tid & 15, which = tid >> 4;
      float v = part[0][row][which] + part[1][row][which]
              + part[2][row][which] + part[3][row][which];
      int n = m0 + row;
      if (which == 0)      attn_src[n * 2]     = v;
      else if (which == 1) attn_src[n * 2 + 1] = v;
      else if (which == 2) attn_trg[n * 2]     = v;
      else                 attn_trg[n * 2 + 1] = v;
    }
    __syncthreads();
  }
}

// ---------------- CSR build: hist + scans (verbatim), then bucketed 2-level scatter ----------------
__global__ __launch_bounds__(256) void hist_kernel(const int* __restrict__ trg, int* __restrict__ count)
{
  int e = blockIdx.x * 256 + threadIdx.x;
  if (e < N_EDGES) {
    int t = trg[e];
    if (t < N_USER) atomicAdd(&count[t], 1);
  }
}

__global__ __launch_bounds__(256) void scan1_kernel(const int* __restrict__ count,
                                                    int* __restrict__ offs, int* __restrict__ aux)
{
  __shared__ int s[256];
  int i = blockIdx.x * 256 + threadIdx.x;
  int v = (i < N_USER) ? count[i] : 0;
  s[threadIdx.x] = v;
  __syncthreads();
  for (int d = 1; d < 256; d <<= 1) {
    int t = (threadIdx.x >= d) ? s[threadIdx.x - d] : 0;
    __syncthreads();
    s[threadIdx.x] += t;
    __syncthreads();
  }
  if (i < N_USER) offs[i] = s[threadIdx.x] - v;
  if (threadIdx.x == 255) aux[blockIdx.x] = s[255];
}

__global__ __launch_bounds__(512) void scan2_kernel(const int* __restrict__ aux, int* __restrict__ auxex)
{
  __shared__ int s[512];
  int v = (threadIdx.x < NB1) ? aux[threadIdx.x] : 0;
  s[threadIdx.x] = v;
  __syncthreads();
  for (int d = 1; d < 512; d <<= 1) {
    int t = (threadIdx.x >= d) ? s[threadIdx.x - d] : 0;
    __syncthreads();
    s[threadIdx.x] += t;
    __syncthreads();
  }
  if (threadIdx.x < NB1) auxex[threadIdx.x] = s[threadIdx.x] - v;
  if (threadIdx.x == 511) auxex[NB1] = s[511];
}

// scan3 also seeds the (64B-padded) bucket cursors: bucket b starts at offs[b*BSZ].
__global__ __launch_bounds__(256) void scan3_kernel(int* __restrict__ offs, int* __restrict__ cursor,
                                                    const int* __restrict__ auxex, int* __restrict__ bcur)
{
  int i = blockIdx.x * 256 + threadIdx.x;
  if (i < N_USER) {
    int o = offs[i] + auxex[blockIdx.x];
    offs[i] = o;
    cursor[i] = o;
    if ((i % BSZ) == 0) bcur[(i / BSZ) * 16] = o;   // 16-int stride = 1 line/bucket
  }
  if (i == 0) offs[N_USER] = auxex[NB1];
}

// Pass B: bin a 2048-edge tile by bucket in LDS, bulk-append contiguous runs per bucket.
__global__ __launch_bounds__(256) void bucket_kernel(
    const int* __restrict__ src, const int* __restrict__ trg,
    int* __restrict__ bcur, uint2* __restrict__ pairbuf)
{
  __shared__ uint2 plds[TILE];
  __shared__ int bcnt[NBUCK], bscan[NBUCK], gbase[NBUCK];
  const int tid = threadIdx.x;
  const int base = blockIdx.x * TILE;
  bcnt[tid] = 0;
  __syncthreads();
  int myb[8], myr[8];
  uint2 myp[8];
  #pragma unroll
  for (int j = 0; j < 8; ++j) {
    int e = base + j * 256 + tid;
    myb[j] = -1;
    if (e < N_EDGES) {
      int t = trg[e];
      if (t < N_USER) {
        int b = t / BSZ;
        myb[j] = b;
        myr[j] = atomicAdd(&bcnt[b], 1);
        myp[j].x = (uint)src[e];
        myp[j].y = (uint)t;
      }
    }
  }
  __syncthreads();
  gbase[tid] = atomicAdd(&bcur[tid * 16], bcnt[tid]);
  bscan[tid] = bcnt[tid];
  __syncthreads();
  for (int d = 1; d < 256; d <<= 1) {
    int v = (tid >= d) ? bscan[tid - d] : 0;
    __syncthreads();
    bscan[tid] += v;
    __syncthreads();
  }
  #pragma unroll
  for (int j = 0; j < 8; ++j)
    if (myb[j] >= 0) plds[bscan[myb[j]] - bcnt[myb[j]] + myr[j]] = myp[j];
  __syncthreads();
  int total = bscan[NBUCK - 1];
  for (int i = tid; i < total; i += 256) {
    uint2 pr = plds[i];
    int b = (int)pr.y / BSZ;
    int idx = gbase[b] + (i - (bscan[b] - bcnt[b]));
    if (idx >= 0 && idx < N_EDGES) pairbuf[idx] = pr;
  }
}

// Pass C: per-bucket scatter with L2 locality, now ALSO computes the per-edge softmax
// weights w = exp(leaky_relu(as+at)) once per edge (1 thread/edge; accum previously
// recomputed this on all 64 lanes -> 64x redundant VALU, the R10 70% VALUBusy).
__global__ __launch_bounds__(256) void fine_kernel(
    const uint2* __restrict__ pairbuf, const int* __restrict__ offs,
    int* __restrict__ cursor, int* __restrict__ csr_src,
    const float* __restrict__ attn_src, const float* __restrict__ attn_trg,
    float2* __restrict__ wgt)
{
  const int b = blockIdx.x;
  int t0 = b * BSZ, t1 = min(t0 + BSZ, N_USER);
  int pbeg = max(0, offs[t0]);
  int pend = min(offs[t1], N_EDGES);
  const float2* as2 = (const float2*)attn_src;
  const float2* at2 = (const float2*)attn_trg;
  for (int i = pbeg + threadIdx.x; i < pend; i += 256) {
    uint2 pr = pairbuf[i];
    int s = min((int)pr.x, N_NODES - 1);
    int t = min((int)pr.y, N_USER - 1);
    float2 as = as2[s];
    float2 at = at2[t];
    float e0 = as.x + at.x; e0 = (e0 > 0.f) ? e0 : 0.2f * e0;
    float e1 = as.y + at.y; e1 = (e1 > 0.f) ? e1 : 0.2f * e1;
    int p = atomicAdd(&cursor[t], 1);
    p = min(max(p, 0), N_EDGES - 1);
    csr_src[p] = s;
    wgt[p] = make_float2(__expf(e0), __expf(e1));
  }
}

// ---------------- per-target accumulation: precomputed weights, 4x MLP unroll ----------------
__global__ __launch_bounds__(256) void accum_kernel(
    const int* __restrict__ offs, const int* __restrict__ csr_src,
    const float2* __restrict__ wgt,
    const uint* __restrict__ hpi, float* __restrict__ x)
{
  const int lane = threadIdx.x & 63, wv = threadIdx.x >> 6;
  int n = blockIdx.x * 4 + wv;
  if (n >= N_USER) return;
  int beg = max(0, offs[n]);
  int end = min(offs[n + 1], N_EDGES);
  float acc0 = 0.f, acc1 = 0.f, den0 = 0.f, den1 = 0.f;
  int i = beg;
  for (; i + 4 <= end; i += 4) {
    int s0 = min(max(csr_src[i], 0), N_NODES - 1);
    int s1 = min(max(csr_src[i + 1], 0), N_NODES - 1);
    int s2 = min(max(csr_src[i + 2], 0), N_NODES - 1);
    int s3 = min(max(csr_src[i + 3], 0), N_NODES - 1);
    float2 W0 = wgt[i];
    float2 W1 = wgt[i + 1];
    float2 W2 = wgt[i + 2];
    float2 W3 = wgt[i + 3];
    uint p0 = hpi[s0 * 64 + lane];
    uint p1 = hpi[s1 * 64 + lane];
    uint p2 = hpi[s2 * 64 + lane];
    uint p3 = hpi[s3 * 64 + lane];
    den0 += W0.x + W1.x + W2.x + W3.x;
    den1 += W0.y + W1.y + W2.y + W3.y;
    acc0 += W0.x * bf2f((ushort)(p0 & 0xffff)) + W1.x * bf2f((ushort)(p1 & 0xffff))
          + W2.x * bf2f((ushort)(p2 & 0xffff)) + W3.x * bf2f((ushort)(p3 & 0xffff));
    acc1 += W0.y * bf2f((ushort)(p0 >> 16)) + W1.y * bf2f((ushort)(p1 >> 16))
          + W2.y * bf2f((ushort)(p2 >> 16)) + W3.y * bf2f((ushort)(p3 >> 16));
  }
  for (; i < end; ++i) {
    int s = min(max(csr_src[i], 0), N_NODES - 1);
    float2 W = wgt[i];
    uint pv = hpi[s * 64 + lane];
    den0 += W.x; den1 += W.y;
    acc0 += W.x * bf2f((ushort)(pv & 0xffff));
    acc1 += W.y * bf2f((ushort)(pv >> 16));
  }
  x[n * 64 + lane] = 0.5f * (acc0 / (den0 + 1e-16f) + acc1 / (den1 + 1e-16f));
}

// ---------------- final: 3 MFMA GEMMs + fused epilogue (R8-R10-verbatim, passed) ----------------
__global__ __launch_bounds__(256) void final_mfma(
    const float* __restrict__ h, const float* __restrict__ x0, const float* __restrict__ x1,
    const float* __restrict__ aa_w1, const float* __restrict__ aa_w2, const float* __restrict__ aa_m,
    const float* __restrict__ fc_w, const float* __restrict__ fc_b, float* __restrict__ out)
{
  __shared__ float aam_s[64], fcw_s[384], fcb_s[2];
  __shared__ float scw0[4][16], scw1[4][16];
  const int tid = threadIdx.x;
  if (tid < 64)  aam_s[tid] = aa_m[tid];
  for (int i = tid; i < 384; i += 256) fcw_s[i] = fc_w[i];
  if (tid < 2)   fcb_s[tid] = fc_b[tid];
  const int lane = tid & 63, wv = tid >> 6, quad = lane >> 4, l15 = lane & 15;
  const int d = wv * 16 + l15;
  short8 b1h[2], b1l[2], b2h[2], b2l[2];
  #pragma unroll
  for (int ks = 0; ks < 2; ++ks) {
    load_split8(aa_w1 + d * 64 + quad * 8 + ks * 32, b1h[ks], b1l[ks]);
    load_split8(aa_w2 + d * 64 + quad * 8 + ks * 32, b2h[ks], b2l[ks]);
  }
  __syncthreads();
  for (int t = blockIdx.x; t < N_USER / 16; t += gridDim.x) {
    int m0 = t * 16, arow = m0 + l15;
    short8 ahh[2], ahl[2], a0h[2], a0l[2], a1h[2], a1l[2];
    #pragma unroll
    for (int ks = 0; ks < 2; ++ks) {
      load_split8(h  + arow * 64 + quad * 8 + ks * 32, ahh[ks], ahl[ks]);
      load_split8(x0 + arow * 64 + quad * 8 + ks * 32, a0h[ks], a0l[ks]);
      load_split8(x1 + arow * 64 + quad * 8 + ks * 32, a1h[ks], a1l[ks]);
    }
    floatx4 t1a = {0.f,0.f,0.f,0.f}, t20a = {0.f,0.f,0.f,0.f}, t21a = {0.f,0.f,0.f,0.f};
    #pragma unroll
    for (int ks = 0; ks < 2; ++ks) {
      t1a  = __builtin_amdgcn_mfma_f32_16x16x32_bf16(ahh[ks], b1h[ks], t1a, 0, 0, 0);
      t1a  = __builtin_amdgcn_mfma_f32_16x16x32_bf16(ahh[ks], b1l[ks], t1a, 0, 0, 0);
      t1a  = __builtin_amdgcn_mfma_f32_16x16x32_bf16(ahl[ks], b1h[ks], t1a, 0, 0, 0);
      t20a = __builtin_amdgcn_mfma_f32_16x16x32_bf16(a0h[ks], b2h[ks], t20a, 0, 0, 0);
      t20a = __builtin_amdgcn_mfma_f32_16x16x32_bf16(a0h[ks], b2l[ks], t20a, 0, 0, 0);
      t20a = __builtin_amdgcn_mfma_f32_16x16x32_bf16(a0l[ks], b2h[ks], t20a, 0, 0, 0);
      t21a = __builtin_amdgcn_mfma_f32_16x16x32_bf16(a1h[ks], b2h[ks], t21a, 0, 0, 0);
      t21a = __builtin_amdgcn_mfma_f32_16x16x32_bf16(a1h[ks], b2l[ks], t21a, 0, 0, 0);
      t21a = __builtin_amdgcn_mfma_f32_16x16x32_bf16(a1l[ks], b2h[ks], t21a, 0, 0, 0);
    }
    float am = aam_s[d];
    #pragma unroll
    for (int r = 0; r < 4; ++r) {
      float q0 = fast_tanh(t1a[r] + t20a[r]);
      float q1 = fast_tanh(t1a[r] + t21a[r]);
      float p0 = q0 * am, p1 = q1 * am;
      #pragma unroll
      for (int m = 1; m < 16; m <<= 1) { p0 += __shfl_xor(p0, m, 64); p1 += __shfl_xor(p1, m, 64); }
      if (l15 == 0) { scw0[wv][quad * 4 + r] = p0; scw1[wv][quad * 4 + r] = p1; }
    }
    __syncthreads();
    if (wv == 0) {
      int row = l15, n = m0 + row;
      float s0 = scw0[0][row] + scw0[1][row] + scw0[2][row] + scw0[3][row];
      float s1 = scw1[0][row] + scw1[1][row] + scw1[2][row] + scw1[3][row];
      float mx = fmaxf(s0, s1);
      float e0 = __expf(s0 - mx), e1 = __expf(s1 - mx);
      float inv = 1.f / (e0 + e1);
      float b0 = e0 * inv, b1 = e1 * inv;
      float pc0 = 0.f, pc1 = 0.f;
      const float* px0 = x0 + n * 64 + quad * 16;
      const float* px1 = x1 + n * 64 + quad * 16;
      #pragma unroll
      for (int jj = 0; jj < 16; jj += 4) {
        float4 v0 = *(const float4*)(px0 + jj);
        float4 v1 = *(const float4*)(px1 + jj);
        float a0[4] = {v0.x, v0.y, v0.z, v0.w};
        float a1[4] = {v1.x, v1.y, v1.z, v1.w};
        #pragma unroll
        for (int c = 0; c < 4; ++c) {
          int o = quad * 16 + jj + c;
          float fv = b0 * a0[c] + b1 * a1[c];
          pc0 += fcw_s[o] * a0[c] + fcw_s[64 + o] * a1[c] + fcw_s[128 + o] * fv;
          pc1 += fcw_s[192 + o] * a0[c] + fcw_s[256 + o] * a1[c] + fcw_s[320 + o] * fv;
        }
      }
      pc0 += __shfl_xor(pc0, 16, 64); pc0 += __shfl_xor(pc0, 32, 64);
      pc1 += __shfl_xor(pc1, 16, 64); pc1 += __shfl_xor(pc1, 32, 64);
      if (lane < 16) {
        float l0 = pc0 + fcb_s[0], l1 = pc1 + fcb_s[1];
        float lm = fmaxf(l0, l1);
        float lse = lm + logf(__expf(l0 - lm) + __expf(l1 - lm));
        out[n * 2] = l0 - lse;
        out[n * 2 + 1] = l1 - lse;
      }
    }
    __syncthreads();
  }
}

extern "C" void kernel_launch(void* const* d_in, const int* in_sizes, int n_in,
                              void* d_out, int out_size, void* d_ws, size_t ws_size,
                              hipStream_t stream)
{
  const float* h     = (const float*)d_in[0];
  const int*   src0  = (const int*)d_in[1];
  const int*   trg0  = (const int*)d_in[2];
  const int*   src1  = (const int*)d_in[3];
  const int*   trg1  = (const int*)d_in[4];
  const float* w0    = (const float*)d_in[5];
  const float* asrc0 = (const float*)d_in[6];
  const float* atrg0 = (const float*)d_in[7];
  const float* w1    = (const float*)d_in[8];
  const float* asrc1 = (const float*)d_in[9];
  const float* atrg1 = (const float*)d_in[10];
  const float* aa_w1 = (const float*)d_in[11];
  const float* aa_w2 = (const float*)d_in[12];
  const float* aa_m  = (const float*)d_in[13];
  const float* fc_w  = (const float*)d_in[14];
  const float* fc_b  = (const float*)d_in[15];
  float* out = (float*)d_out;

  char* ws = (char*)d_ws;
  size_t off = 0;
  auto alloc = [&](size_t bytes) -> void* {
    void* p = ws + off;
    off = (off + bytes + 255) & ~(size_t)255;
    return p;
  };
  // total ~106 MB (== R2/R7 proven footprint)
  uint*   hpi      = (uint*)alloc((size_t)N_NODES * 64 * 4);     // 25.6 MB, reused per layer
  float*  attn_src = (float*)alloc((size_t)N_NODES * 2 * 4);
  float*  attn_trg = (float*)alloc((size_t)N_NODES * 2 * 4);
  float*  x0       = (float*)alloc((size_t)N_USER * 64 * 4);     // 23 MB
  float*  x1       = (float*)alloc((size_t)N_USER * 64 * 4);
  int*    count    = (int*)alloc((size_t)N_USER * 4);
  int*    offs     = (int*)alloc((size_t)(N_USER + 1) * 4);
  int*    cursor   = (int*)alloc((size_t)N_USER * 4);
  int*    aux      = (int*)alloc((size_t)NB1 * 4);
  int*    auxex    = (int*)alloc((size_t)(NB1 + 1) * 4);
  int*    csr      = (int*)alloc((size_t)N_EDGES * 4);           // 6.4 MB, reused per layer
  uint2*  pairbuf  = (uint2*)alloc((size_t)N_EDGES * 8);         // 12.8 MB, reused per layer
  float2* wgt      = (float2*)alloc((size_t)N_EDGES * 8);        // 12.8 MB, reused per layer
  int*    bcur     = (int*)alloc((size_t)NBUCK * 16 * 4);        // padded bucket cursors

  const int EB = (N_EDGES + 255) / 256;      // 6250
  const int TB = (N_EDGES + TILE - 1) / TILE;// 782
  for (int layer = 0; layer < 2; ++layer) {
    const float* w    = layer ? w1 : w0;
    const float* asrc = layer ? asrc1 : asrc0;
    const float* atrg = layer ? atrg1 : atrg0;
    const int*   src  = layer ? src1 : src0;
    const int*   trg  = layer ? trg1 : trg0;
    float*       x    = layer ? x1 : x0;
    hipLaunchKernelGGL(hp_mfma, dim3(1024), dim3(256), 0, stream,
                       h, w, asrc, atrg, hpi, attn_src, attn_trg);
    hipMemsetAsync(count, 0, (size_t)N_USER * 4, stream);
    hipLaunchKernelGGL(hist_kernel, dim3(EB), dim3(256), 0, stream, trg, count);
    hipLaunchKernelGGL(scan1_kernel, dim3(NB1), dim3(256), 0, stream, count, offs, aux);
    hipLaunchKernelGGL(scan2_kernel, dim3(1), dim3(512), 0, stream, aux, auxex);
    hipLaunchKernelGGL(scan3_kernel, dim3(NB1), dim3(256), 0, stream, offs, cursor, auxex, bcur);
    hipLaunchKernelGGL(bucket_kernel, dim3(TB), dim3(256), 0, stream, src, trg, bcur, pairbuf);
    hipLaunchKernelGGL(fine_kernel, dim3(NBUCK), dim3(256), 0, stream,
                       pairbuf, offs, cursor, csr, attn_src, attn_trg, wgt);
    hipLaunchKernelGGL(accum_kernel, dim3(N_USER / 4), dim3(256), 0, stream,
                       offs, csr, wgt, hpi, x);
  }
  hipLaunchKernelGGL(final_mfma, dim3(1875), dim3(256), 0, stream,
                     h, x0, x1, aa_w1, aa_w2, aa_m, fc_w, fc_b, out);
}

// Round 12
// 615.862 us; speedup vs baseline: 2.2406x; 1.0261x over previous
//
#include <hip/hip_runtime.h>
#include <hip/hip_bf16.h>
#include <math.h>

#define N_NODES 100000
#define N_EDGES 1600000
#define N_USER  90000
#define NB1     352   // ceil(N_USER/256)
#define NBUCK   256
#define BSZ     352   // targets per bucket; 256*352 = 90112 >= N_USER
#define TILE    2048  // edges per bucket_kernel block

typedef __attribute__((ext_vector_type(8))) short  short8;   // 8 bf16 (4 VGPRs) MFMA A/B frag
typedef __attribute__((ext_vector_type(4))) float  floatx4;  // MFMA C/D frag
typedef unsigned int  uint;
typedef unsigned short ushort;

__device__ __forceinline__ ushort f2bf(float x) {            // RNE fp32 -> bf16
  uint u = __float_as_uint(x);
  u += 0x7fffu + ((u >> 16) & 1u);
  return (ushort)(u >> 16);
}
__device__ __forceinline__ float bf2f(ushort v) { return __uint_as_float(((uint)v) << 16); }

__device__ __forceinline__ void split8(const float v[8], short8& hi, short8& lo) {
  #pragma unroll
  for (int j = 0; j < 8; ++j) {
    ushort h = f2bf(v[j]);
    hi[j] = (short)h;
    lo[j] = (short)f2bf(v[j] - bf2f(h));
  }
}
__device__ __forceinline__ void load_split8(const float* p, short8& hi, short8& lo) {
  const float4* q = (const float4*)p;
  float4 a = q[0], b = q[1];
  float v[8] = {a.x, a.y, a.z, a.w, b.x, b.y, b.z, b.w};
  split8(v, hi, lo);
}
__device__ __forceinline__ float fast_tanh(float x) {
  float t = __expf(2.f * x);
  return 1.f - 2.f / (t + 1.f);
}

// ---------------- hp via MFMA -> packed bf16, exact fp32 logits (one layer) ----------------
__global__ __launch_bounds__(256) void hp_mfma(
    const float* __restrict__ h, const float* __restrict__ w,
    const float* __restrict__ a_src, const float* __restrict__ a_trg,
    uint* __restrict__ hpi, float* __restrict__ attn_src, float* __restrict__ attn_trg)
{
  __shared__ float part[4][16][4];          // [wave][row][as0,as1,at0,at1]
  const int tid = threadIdx.x, lane = tid & 63, wv = tid >> 6;
  const int quad = lane >> 4, l15 = lane & 15;
  const int o = wv * 16 + l15;              // wave's 16-col slice of the 64 outputs
  const float vas0 = a_src[o], vas1 = a_src[64 + o];
  const float vat0 = a_trg[o], vat1 = a_trg[64 + o];
  short8 b0h[2], b0l[2], b1h[2], b1l[2];    // B frags: head0/head1 x ksteps
  #pragma unroll
  for (int ks = 0; ks < 2; ++ks) {
    float v0[8], v1[8];
    #pragma unroll
    for (int j = 0; j < 8; ++j) {
      int k = quad * 8 + j + ks * 32;       // f index
      v0[j] = w[k * 64 + o];                // w[0][f][o]
      v1[j] = w[4096 + k * 64 + o];         // w[1][f][o]
    }
    split8(v0, b0h[ks], b0l[ks]);
    split8(v1, b1h[ks], b1l[ks]);
  }
  for (int t = blockIdx.x; t < N_NODES / 16; t += gridDim.x) {
    int m0 = t * 16, arow = m0 + l15;
    short8 ah[2], al[2];
    #pragma unroll
    for (int ks = 0; ks < 2; ++ks)
      load_split8(h + arow * 64 + quad * 8 + ks * 32, ah[ks], al[ks]);
    floatx4 c0 = {0.f, 0.f, 0.f, 0.f}, c1 = {0.f, 0.f, 0.f, 0.f};
    #pragma unroll
    for (int ks = 0; ks < 2; ++ks) {
      c0 = __builtin_amdgcn_mfma_f32_16x16x32_bf16(ah[ks], b0h[ks], c0, 0, 0, 0);
      c0 = __builtin_amdgcn_mfma_f32_16x16x32_bf16(ah[ks], b0l[ks], c0, 0, 0, 0);
      c0 = __builtin_amdgcn_mfma_f32_16x16x32_bf16(al[ks], b0h[ks], c0, 0, 0, 0);
      c1 = __builtin_amdgcn_mfma_f32_16x16x32_bf16(ah[ks], b1h[ks], c1, 0, 0, 0);
      c1 = __builtin_amdgcn_mfma_f32_16x16x32_bf16(ah[ks], b1l[ks], c1, 0, 0, 0);
      c1 = __builtin_amdgcn_mfma_f32_16x16x32_bf16(al[ks], b1h[ks], c1, 0, 0, 0);
    }
    #pragma unroll
    for (int r = 0; r < 4; ++r) {
      int n = m0 + quad * 4 + r;
      hpi[n * 64 + o] = (uint)f2bf(c0[r]) | ((uint)f2bf(c1[r]) << 16);
    }
    #pragma unroll
    for (int r = 0; r < 4; ++r) {
      float pas0 = c0[r] * vas0, pas1 = c1[r] * vas1;
      float pat0 = c0[r] * vat0, pat1 = c1[r] * vat1;
      #pragma unroll
      for (int m = 1; m < 16; m <<= 1) {
        pas0 += __shfl_xor(pas0, m, 64); pas1 += __shfl_xor(pas1, m, 64);
        pat0 += __shfl_xor(pat0, m, 64); pat1 += __shfl_xor(pat1, m, 64);
      }
      if (l15 == 0) {
        part[wv][quad * 4 + r][0] = pas0; part[wv][quad * 4 + r][1] = pas1;
        part[wv][quad * 4 + r][2] = pat0; part[wv][quad * 4 + r][3] = pat1;
      }
    }
    __syncthreads();
    if (tid < 64) {
      int row = tid & 15, which = tid >> 4;
      float v = part[0][row][which] + part[1][row][which]
              + part[2][row][which] + part[3][row][which];
      int n = m0 + row;
      if (which == 0)      attn_src[n * 2]     = v;
      else if (which == 1) attn_src[n * 2 + 1] = v;
      else if (which == 2) attn_trg[n * 2]     = v;
      else                 attn_trg[n * 2 + 1] = v;
    }
    __syncthreads();
  }
}

// ---------------- CSR build: hist + scans (verbatim), then bucketed 2-level scatter ----------------
__global__ __launch_bounds__(256) void hist_kernel(const int* __restrict__ trg, int* __restrict__ count)
{
  int e = blockIdx.x * 256 + threadIdx.x;
  if (e < N_EDGES) {
    int t = trg[e];
    if (t < N_USER) atomicAdd(&count[t], 1);
  }
}

__global__ __launch_bounds__(256) void scan1_kernel(const int* __restrict__ count,
                                                    int* __restrict__ offs, int* __restrict__ aux)
{
  __shared__ int s[256];
  int i = blockIdx.x * 256 + threadIdx.x;
  int v = (i < N_USER) ? count[i] : 0;
  s[threadIdx.x] = v;
  __syncthreads();
  for (int d = 1; d < 256; d <<= 1) {
    int t = (threadIdx.x >= d) ? s[threadIdx.x - d] : 0;
    __syncthreads();
    s[threadIdx.x] += t;
    __syncthreads();
  }
  if (i < N_USER) offs[i] = s[threadIdx.x] - v;
  if (threadIdx.x == 255) aux[blockIdx.x] = s[255];
}

__global__ __launch_bounds__(512) void scan2_kernel(const int* __restrict__ aux, int* __restrict__ auxex)
{
  __shared__ int s[512];
  int v = (threadIdx.x < NB1) ? aux[threadIdx.x] : 0;
  s[threadIdx.x] = v;
  __syncthreads();
  for (int d = 1; d < 512; d <<= 1) {
    int t = (threadIdx.x >= d) ? s[threadIdx.x - d] : 0;
    __syncthreads();
    s[threadIdx.x] += t;
    __syncthreads();
  }
  if (threadIdx.x < NB1) auxex[threadIdx.x] = s[threadIdx.x] - v;
  if (threadIdx.x == 511) auxex[NB1] = s[511];
}

// scan3 also seeds the (64B-padded) bucket cursors: bucket b starts at offs[b*BSZ].
__global__ __launch_bounds__(256) void scan3_kernel(int* __restrict__ offs, int* __restrict__ cursor,
                                                    const int* __restrict__ auxex, int* __restrict__ bcur)
{
  int i = blockIdx.x * 256 + threadIdx.x;
  if (i < N_USER) {
    int o = offs[i] + auxex[blockIdx.x];
    offs[i] = o;
    cursor[i] = o;
    if ((i % BSZ) == 0) bcur[(i / BSZ) * 16] = o;   // 16-int stride = 1 line/bucket
  }
  if (i == 0) offs[N_USER] = auxex[NB1];
}

// Pass B: bin a 2048-edge tile by bucket in LDS, bulk-append contiguous runs per bucket.
__global__ __launch_bounds__(256) void bucket_kernel(
    const int* __restrict__ src, const int* __restrict__ trg,
    int* __restrict__ bcur, uint2* __restrict__ pairbuf)
{
  __shared__ uint2 plds[TILE];
  __shared__ int bcnt[NBUCK], bscan[NBUCK], gbase[NBUCK];
  const int tid = threadIdx.x;
  const int base = blockIdx.x * TILE;
  bcnt[tid] = 0;
  __syncthreads();
  int myb[8], myr[8];
  uint2 myp[8];
  #pragma unroll
  for (int j = 0; j < 8; ++j) {
    int e = base + j * 256 + tid;
    myb[j] = -1;
    if (e < N_EDGES) {
      int t = trg[e];
      if (t < N_USER) {
        int b = t / BSZ;
        myb[j] = b;
        myr[j] = atomicAdd(&bcnt[b], 1);
        myp[j].x = (uint)src[e];
        myp[j].y = (uint)t;
      }
    }
  }
  __syncthreads();
  gbase[tid] = atomicAdd(&bcur[tid * 16], bcnt[tid]);
  bscan[tid] = bcnt[tid];
  __syncthreads();
  for (int d = 1; d < 256; d <<= 1) {
    int v = (tid >= d) ? bscan[tid - d] : 0;
    __syncthreads();
    bscan[tid] += v;
    __syncthreads();
  }
  #pragma unroll
  for (int j = 0; j < 8; ++j)
    if (myb[j] >= 0) plds[bscan[myb[j]] - bcnt[myb[j]] + myr[j]] = myp[j];
  __syncthreads();
  int total = bscan[NBUCK - 1];
  for (int i = tid; i < total; i += 256) {
    uint2 pr = plds[i];
    int b = (int)pr.y / BSZ;
    int idx = gbase[b] + (i - (bscan[b] - bcnt[b]));
    if (idx >= 0 && idx < N_EDGES) pairbuf[idx] = pr;
  }
}

// Pass C: per-bucket scatter with L2 locality + per-edge softmax weight precompute.
__global__ __launch_bounds__(256) void fine_kernel(
    const uint2* __restrict__ pairbuf, const int* __restrict__ offs,
    int* __restrict__ cursor, int* __restrict__ csr_src,
    const float* __restrict__ attn_src, const float* __restrict__ attn_trg,
    float2* __restrict__ wgt)
{
  const int b = blockIdx.x;
  int t0 = b * BSZ, t1 = min(t0 + BSZ, N_USER);
  int pbeg = max(0, offs[t0]);
  int pend = min(offs[t1], N_EDGES);
  const float2* as2 = (const float2*)attn_src;
  const float2* at2 = (const float2*)attn_trg;
  for (int i = pbeg + threadIdx.x; i < pend; i += 256) {
    uint2 pr = pairbuf[i];
    int s = min((int)pr.x, N_NODES - 1);
    int t = min((int)pr.y, N_USER - 1);
    float2 as = as2[s];
    float2 at = at2[t];
    float e0 = as.x + at.x; e0 = (e0 > 0.f) ? e0 : 0.2f * e0;
    float e1 = as.y + at.y; e1 = (e1 > 0.f) ? e1 : 0.2f * e1;
    int p = atomicAdd(&cursor[t], 1);
    p = min(max(p, 0), N_EDGES - 1);
    csr_src[p] = s;
    wgt[p] = make_float2(__expf(e0), __expf(e1));
  }
}

// ---------------- per-target accumulation: precomputed weights, 4x MLP unroll ----------------
__global__ __launch_bounds__(256) void accum_kernel(
    const int* __restrict__ offs, const int* __restrict__ csr_src,
    const float2* __restrict__ wgt,
    const uint* __restrict__ hpi, float* __restrict__ x)
{
  const int lane = threadIdx.x & 63, wv = threadIdx.x >> 6;
  int n = blockIdx.x * 4 + wv;
  if (n >= N_USER) return;
  int beg = max(0, offs[n]);
  int end = min(offs[n + 1], N_EDGES);
  float acc0 = 0.f, acc1 = 0.f, den0 = 0.f, den1 = 0.f;
  int i = beg;
  for (; i + 4 <= end; i += 4) {
    int s0 = min(max(csr_src[i], 0), N_NODES - 1);
    int s1 = min(max(csr_src[i + 1], 0), N_NODES - 1);
    int s2 = min(max(csr_src[i + 2], 0), N_NODES - 1);
    int s3 = min(max(csr_src[i + 3], 0), N_NODES - 1);
    float2 W0 = wgt[i];
    float2 W1 = wgt[i + 1];
    float2 W2 = wgt[i + 2];
    float2 W3 = wgt[i + 3];
    uint p0 = hpi[s0 * 64 + lane];
    uint p1 = hpi[s1 * 64 + lane];
    uint p2 = hpi[s2 * 64 + lane];
    uint p3 = hpi[s3 * 64 + lane];
    den0 += W0.x + W1.x + W2.x + W3.x;
    den1 += W0.y + W1.y + W2.y + W3.y;
    acc0 += W0.x * bf2f((ushort)(p0 & 0xffff)) + W1.x * bf2f((ushort)(p1 & 0xffff))
          + W2.x * bf2f((ushort)(p2 & 0xffff)) + W3.x * bf2f((ushort)(p3 & 0xffff));
    acc1 += W0.y * bf2f((ushort)(p0 >> 16)) + W1.y * bf2f((ushort)(p1 >> 16))
          + W2.y * bf2f((ushort)(p2 >> 16)) + W3.y * bf2f((ushort)(p3 >> 16));
  }
  for (; i < end; ++i) {
    int s = min(max(csr_src[i], 0), N_NODES - 1);
    float2 W = wgt[i];
    uint pv = hpi[s * 64 + lane];
    den0 += W.x; den1 += W.y;
    acc0 += W.x * bf2f((ushort)(pv & 0xffff));
    acc1 += W.y * bf2f((ushort)(pv >> 16));
  }
  x[n * 64 + lane] = 0.5f * (acc0 / (den0 + 1e-16f) + acc1 / (den1 + 1e-16f));
}

// ---------------- final: 3 MFMA GEMMs + fused epilogue ----------------
// R11 profile: 76 us, MfmaUtil 3%, VALUBusy 33% -- stage 2 ran on wave 0 only
// (waves 1-3 idle at barrier). Now distributed: wave wv covers row wv*4+quad,
// lane (quad,l15) covers o = l15*4..+3 via float4 loads; 4-step 16-lane reduce.
__global__ __launch_bounds__(256) void final_mfma(
    const float* __restrict__ h, const float* __restrict__ x0, const float* __restrict__ x1,
    const float* __restrict__ aa_w1, const float* __restrict__ aa_w2, const float* __restrict__ aa_m,
    const float* __restrict__ fc_w, const float* __restrict__ fc_b, float* __restrict__ out)
{
  __shared__ float aam_s[64], fcw_s[384], fcb_s[2];
  __shared__ float scw0[4][16], scw1[4][16];
  const int tid = threadIdx.x;
  if (tid < 64)  aam_s[tid] = aa_m[tid];
  for (int i = tid; i < 384; i += 256) fcw_s[i] = fc_w[i];
  if (tid < 2)   fcb_s[tid] = fc_b[tid];
  const int lane = tid & 63, wv = tid >> 6, quad = lane >> 4, l15 = lane & 15;
  const int d = wv * 16 + l15;
  short8 b1h[2], b1l[2], b2h[2], b2l[2];
  #pragma unroll
  for (int ks = 0; ks < 2; ++ks) {
    load_split8(aa_w1 + d * 64 + quad * 8 + ks * 32, b1h[ks], b1l[ks]);
    load_split8(aa_w2 + d * 64 + quad * 8 + ks * 32, b2h[ks], b2l[ks]);
  }
  __syncthreads();
  for (int t = blockIdx.x; t < N_USER / 16; t += gridDim.x) {
    int m0 = t * 16, arow = m0 + l15;
    short8 ahh[2], ahl[2], a0h[2], a0l[2], a1h[2], a1l[2];
    #pragma unroll
    for (int ks = 0; ks < 2; ++ks) {
      load_split8(h  + arow * 64 + quad * 8 + ks * 32, ahh[ks], ahl[ks]);
      load_split8(x0 + arow * 64 + quad * 8 + ks * 32, a0h[ks], a0l[ks]);
      load_split8(x1 + arow * 64 + quad * 8 + ks * 32, a1h[ks], a1l[ks]);
    }
    floatx4 t1a = {0.f,0.f,0.f,0.f}, t20a = {0.f,0.f,0.f,0.f}, t21a = {0.f,0.f,0.f,0.f};
    #pragma unroll
    for (int ks = 0; ks < 2; ++ks) {
      t1a  = __builtin_amdgcn_mfma_f32_16x16x32_bf16(ahh[ks], b1h[ks], t1a, 0, 0, 0);
      t1a  = __builtin_amdgcn_mfma_f32_16x16x32_bf16(ahh[ks], b1l[ks], t1a, 0, 0, 0);
      t1a  = __builtin_amdgcn_mfma_f32_16x16x32_bf16(ahl[ks], b1h[ks], t1a, 0, 0, 0);
      t20a = __builtin_amdgcn_mfma_f32_16x16x32_bf16(a0h[ks], b2h[ks], t20a, 0, 0, 0);
      t20a = __builtin_amdgcn_mfma_f32_16x16x32_bf16(a0h[ks], b2l[ks], t20a, 0, 0, 0);
      t20a = __builtin_amdgcn_mfma_f32_16x16x32_bf16(a0l[ks], b2h[ks], t20a, 0, 0, 0);
      t21a = __builtin_amdgcn_mfma_f32_16x16x32_bf16(a1h[ks], b2h[ks], t21a, 0, 0, 0);
      t21a = __builtin_amdgcn_mfma_f32_16x16x32_bf16(a1h[ks], b2l[ks], t21a, 0, 0, 0);
      t21a = __builtin_amdgcn_mfma_f32_16x16x32_bf16(a1l[ks], b2h[ks], t21a, 0, 0, 0);
    }
    float am = aam_s[d];
    #pragma unroll
    for (int r = 0; r < 4; ++r) {
      float q0 = fast_tanh(t1a[r] + t20a[r]);
      float q1 = fast_tanh(t1a[r] + t21a[r]);
      float p0 = q0 * am, p1 = q1 * am;
      #pragma unroll
      for (int m = 1; m < 16; m <<= 1) { p0 += __shfl_xor(p0, m, 64); p1 += __shfl_xor(p1, m, 64); }
      if (l15 == 0) { scw0[wv][quad * 4 + r] = p0; scw1[wv][quad * 4 + r] = p1; }
    }
    __syncthreads();
    // stage 2 (all 4 waves): row = wv*4+quad, o = l15*4..+3
    {
      int row = wv * 4 + quad, n = m0 + row;
      float s0 = scw0[0][row] + scw0[1][row] + scw0[2][row] + scw0[3][row];
      float s1 = scw1[0][row] + scw1[1][row] + scw1[2][row] + scw1[3][row];
      float mx = fmaxf(s0, s1);
      float e0 = __expf(s0 - mx), e1 = __expf(s1 - mx);
      float inv = 1.f / (e0 + e1);
      float b0 = e0 * inv, b1 = e1 * inv;
      float4 v0 = *(const float4*)(x0 + n * 64 + l15 * 4);
      float4 v1 = *(const float4*)(x1 + n * 64 + l15 * 4);
      float a0[4] = {v0.x, v0.y, v0.z, v0.w};
      float a1[4] = {v1.x, v1.y, v1.z, v1.w};
      float pc0 = 0.f, pc1 = 0.f;
      #pragma unroll
      for (int c = 0; c < 4; ++c) {
        int o = l15 * 4 + c;
        float fv = b0 * a0[c] + b1 * a1[c];
        pc0 += fcw_s[o] * a0[c] + fcw_s[64 + o] * a1[c] + fcw_s[128 + o] * fv;
        pc1 += fcw_s[192 + o] * a0[c] + fcw_s[256 + o] * a1[c] + fcw_s[320 + o] * fv;
      }
      #pragma unroll
      for (int m = 1; m < 16; m <<= 1) { pc0 += __shfl_xor(pc0, m, 64); pc1 += __shfl_xor(pc1, m, 64); }
      if (l15 == 0) {
        float l0 = pc0 + fcb_s[0], l1 = pc1 + fcb_s[1];
        float lm = fmaxf(l0, l1);
        float lse = lm + logf(__expf(l0 - lm) + __expf(l1 - lm));
        out[n * 2] = l0 - lse;
        out[n * 2 + 1] = l1 - lse;
      }
    }
    __syncthreads();
  }
}

extern "C" void kernel_launch(void* const* d_in, const int* in_sizes, int n_in,
                              void* d_out, int out_size, void* d_ws, size_t ws_size,
                              hipStream_t stream)
{
  const float* h     = (const float*)d_in[0];
  const int*   src0  = (const int*)d_in[1];
  const int*   trg0  = (const int*)d_in[2];
  const int*   src1  = (const int*)d_in[3];
  const int*   trg1  = (const int*)d_in[4];
  const float* w0    = (const float*)d_in[5];
  const float* asrc0 = (const float*)d_in[6];
  const float* atrg0 = (const float*)d_in[7];
  const float* w1    = (const float*)d_in[8];
  const float* asrc1 = (const float*)d_in[9];
  const float* atrg1 = (const float*)d_in[10];
  const float* aa_w1 = (const float*)d_in[11];
  const float* aa_w2 = (const float*)d_in[12];
  const float* aa_m  = (const float*)d_in[13];
  const float* fc_w  = (const float*)d_in[14];
  const float* fc_b  = (const float*)d_in[15];
  float* out = (float*)d_out;

  char* ws = (char*)d_ws;
  size_t off = 0;
  auto alloc = [&](size_t bytes) -> void* {
    void* p = ws + off;
    off = (off + bytes + 255) & ~(size_t)255;
    return p;
  };
  // total ~106 MB (== R2/R7 proven footprint)
  uint*   hpi      = (uint*)alloc((size_t)N_NODES * 64 * 4);     // 25.6 MB, reused per layer
  float*  attn_src = (float*)alloc((size_t)N_NODES * 2 * 4);
  float*  attn_trg = (float*)alloc((size_t)N_NODES * 2 * 4);
  float*  x0       = (float*)alloc((size_t)N_USER * 64 * 4);     // 23 MB
  float*  x1       = (float*)alloc((size_t)N_USER * 64 * 4);
  int*    count    = (int*)alloc((size_t)N_USER * 4);
  int*    offs     = (int*)alloc((size_t)(N_USER + 1) * 4);
  int*    cursor   = (int*)alloc((size_t)N_USER * 4);
  int*    aux      = (int*)alloc((size_t)NB1 * 4);
  int*    auxex    = (int*)alloc((size_t)(NB1 + 1) * 4);
  int*    csr      = (int*)alloc((size_t)N_EDGES * 4);           // 6.4 MB, reused per layer
  uint2*  pairbuf  = (uint2*)alloc((size_t)N_EDGES * 8);         // 12.8 MB, reused per layer
  float2* wgt      = (float2*)alloc((size_t)N_EDGES * 8);        // 12.8 MB, reused per layer
  int*    bcur     = (int*)alloc((size_t)NBUCK * 16 * 4);        // padded bucket cursors

  const int EB = (N_EDGES + 255) / 256;      // 6250
  const int TB = (N_EDGES + TILE - 1) / TILE;// 782
  for (int layer = 0; layer < 2; ++layer) {
    const float* w    = layer ? w1 : w0;
    const float* asrc = layer ? asrc1 : asrc0;
    const float* atrg = layer ? atrg1 : atrg0;
    const int*   src  = layer ? src1 : src0;
    const int*   trg  = layer ? trg1 : trg0;
    float*       x    = layer ? x1 : x0;
    hipLaunchKernelGGL(hp_mfma, dim3(1024), dim3(256), 0, stream,
                       h, w, asrc, atrg, hpi, attn_src, attn_trg);
    hipMemsetAsync(count, 0, (size_t)N_USER * 4, stream);
    hipLaunchKernelGGL(hist_kernel, dim3(EB), dim3(256), 0, stream, trg, count);
    hipLaunchKernelGGL(scan1_kernel, dim3(NB1), dim3(256), 0, stream, count, offs, aux);
    hipLaunchKernelGGL(scan2_kernel, dim3(1), dim3(512), 0, stream, aux, auxex);
    hipLaunchKernelGGL(scan3_kernel, dim3(NB1), dim3(256), 0, stream, offs, cursor, auxex, bcur);
    hipLaunchKernelGGL(bucket_kernel, dim3(TB), dim3(256), 0, stream, src, trg, bcur, pairbuf);
    hipLaunchKernelGGL(fine_kernel, dim3(NBUCK), dim3(256), 0, stream,
                       pairbuf, offs, cursor, csr, attn_src, attn_trg, wgt);
    hipLaunchKernelGGL(accum_kernel, dim3(N_USER / 4), dim3(256), 0, stream,
                       offs, csr, wgt, hpi, x);
  }
  hipLaunchKernelGGL(final_mfma, dim3(1875), dim3(256), 0, stream,
                     h, x0, x1, aa_w1, aa_w2, aa_m, fc_w, fc_b, out);
}